// Round 1
// baseline (1234.059 us; speedup 1.0000x reference)
//
#include <hip/hip_runtime.h>
#include <hip/hip_bf16.h>
#include <math.h>

#define N_USERS 50000
#define N_ITEMS 50000
#define NN      100000
#define E_PER_  400000
#define E_TOT   800000
#define FDIM    128
#define NH      4
#define HD      32

__device__ __forceinline__ float gelu_exact(float x) {
    return 0.5f * x * (1.0f + erff(x * 0.70710678118654752f));
}
__device__ __forceinline__ unsigned f32_enc(float f) {
    unsigned u = __float_as_uint(f);
    return (u & 0x80000000u) ? ~u : (u | 0x80000000u);
}
__device__ __forceinline__ float f32_dec(unsigned u) {
    return (u & 0x80000000u) ? __uint_as_float(u & 0x7fffffffu) : __uint_as_float(~u);
}

// ---------------------------------------------------------------------------
// Kernel 1: C[M,384] = X[M,128] @ W[128,384] + b  (per side), split to k/q/v.
// BM=128, BN=128 (one chunk = exactly k, q, or v), 256 threads, 8x8 micro.
// ---------------------------------------------------------------------------
__global__ __launch_bounds__(256) void kqv_gemm(
    const float* __restrict__ X, const float* __restrict__ W,
    const float* __restrict__ b, float* __restrict__ q_all,
    float* __restrict__ k_raw, float* __restrict__ v_raw,
    int M, int side_off)
{
    __shared__ float Xs[128][128];   // transposed: Xs[k][r]
    __shared__ float Ws[128][128];   // Ws[k][c]
    const int t = threadIdx.x;
    const int m0 = blockIdx.x * 128;
    const int n0 = blockIdx.y * 128;   // 0,128,256 -> k,q,v

    #pragma unroll
    for (int j = 0; j < 16; ++j) {
        int idx = t + j * 256;           // 4096 float4 slots
        int r = idx & 127, cp = idx >> 7;
        float4 v = make_float4(0.f, 0.f, 0.f, 0.f);
        int row = m0 + r;
        if (row < M) v = *reinterpret_cast<const float4*>(X + (size_t)row * FDIM + cp * 4);
        Xs[cp * 4 + 0][r] = v.x; Xs[cp * 4 + 1][r] = v.y;
        Xs[cp * 4 + 2][r] = v.z; Xs[cp * 4 + 3][r] = v.w;
    }
    #pragma unroll
    for (int j = 0; j < 16; ++j) {
        int idx = t + j * 256;
        int row = idx >> 5, cp = idx & 31;
        float4 v = *reinterpret_cast<const float4*>(W + (size_t)row * 384 + n0 + cp * 4);
        *reinterpret_cast<float4*>(&Ws[row][cp * 4]) = v;
    }
    __syncthreads();

    const int ty = t >> 4, tx = t & 15;
    const int r0 = ty * 8, c0 = tx * 8;
    float acc[8][8] = {};
    for (int k = 0; k < 128; ++k) {
        float4 a0 = *reinterpret_cast<const float4*>(&Xs[k][r0]);
        float4 a1 = *reinterpret_cast<const float4*>(&Xs[k][r0 + 4]);
        float4 b0 = *reinterpret_cast<const float4*>(&Ws[k][c0]);
        float4 b1 = *reinterpret_cast<const float4*>(&Ws[k][c0 + 4]);
        float a[8] = {a0.x, a0.y, a0.z, a0.w, a1.x, a1.y, a1.z, a1.w};
        float bb[8] = {b0.x, b0.y, b0.z, b0.w, b1.x, b1.y, b1.z, b1.w};
        #pragma unroll
        for (int i = 0; i < 8; ++i)
            #pragma unroll
            for (int j = 0; j < 8; ++j)
                acc[i][j] = fmaf(a[i], bb[j], acc[i][j]);
    }

    float* dst = (blockIdx.y == 0) ? k_raw : (blockIdx.y == 1) ? q_all : v_raw;
    float bv[8];
    #pragma unroll
    for (int j = 0; j < 8; ++j) bv[j] = b[n0 + c0 + j];
    for (int i = 0; i < 8; ++i) {
        int row = m0 + r0 + i;
        if (row >= M) break;
        size_t o = (size_t)(side_off + row) * FDIM + c0;
        float4 s0, s1;
        s0.x = acc[i][0] + bv[0]; s0.y = acc[i][1] + bv[1];
        s0.z = acc[i][2] + bv[2]; s0.w = acc[i][3] + bv[3];
        s1.x = acc[i][4] + bv[4]; s1.y = acc[i][5] + bv[5];
        s1.z = acc[i][6] + bv[6]; s1.w = acc[i][7] + bv[7];
        *reinterpret_cast<float4*>(dst + o)     = s0;
        *reinterpret_cast<float4*>(dst + o + 4) = s1;
    }
}

// ---------------------------------------------------------------------------
// Kernel 2: per-head relation transform  kk[n,h,e] = sum_d k_raw[n,h,d]*Wk[h*2+et][d][e]
// 8 nodes per block; Wk/Wv (et-selected) staged in LDS.
// ---------------------------------------------------------------------------
__global__ __launch_bounds__(256) void rel_kernel(
    const float* __restrict__ k_raw, const float* __restrict__ v_raw,
    const float* __restrict__ Wk_rel, const float* __restrict__ Wv_rel,
    float* __restrict__ kk, float* __restrict__ vv)
{
    __shared__ float Wk[4][32][32];
    __shared__ float Wv[4][32][32];
    __shared__ float rowk[8][128];
    __shared__ float rowv[8][128];
    const int t = threadIdx.x;
    const int nodeBase = blockIdx.x * 8;
    const int et = (nodeBase >= N_USERS) ? 1 : 0;

    #pragma unroll
    for (int j = 0; j < 16; ++j) {
        int idx = t + j * 256;        // 0..4095
        int h = idx >> 10, rem = idx & 1023;
        Wk[h][rem >> 5][rem & 31] = Wk_rel[(size_t)(h * 2 + et) * 1024 + rem];
        Wv[h][rem >> 5][rem & 31] = Wv_rel[(size_t)(h * 2 + et) * 1024 + rem];
    }
    #pragma unroll
    for (int j = 0; j < 4; ++j) {
        int idx = t + j * 256;
        int n = idx >> 7, c = idx & 127;
        rowk[n][c] = k_raw[(size_t)(nodeBase + n) * FDIM + c];
        rowv[n][c] = v_raw[(size_t)(nodeBase + n) * FDIM + c];
    }
    __syncthreads();

    const int which = t >> 7;        // 0 = k, 1 = v
    const int c = t & 127, h = c >> 5, e = c & 31;
    const float (*Wm)[32][32] = which ? Wv : Wk;
    const float (*rows)[128]  = which ? rowv : rowk;
    float* outp = which ? vv : kk;
    for (int n = 0; n < 8; ++n) {
        float s = 0.f;
        #pragma unroll
        for (int d = 0; d < 32; ++d)
            s = fmaf(rows[n][h * 32 + d], Wm[h][d][e], s);
        outp[(size_t)(nodeBase + n) * FDIM + c] = s;
    }
}

// ---------------------------------------------------------------------------
// Kernel 3: wave per edge — alpha[e,h] = dot(q[dst,h], kk[src,h]) * p[h] / sqrt(D)
// plus segment-max via monotone-uint atomicMax.
// ---------------------------------------------------------------------------
__global__ __launch_bounds__(256) void edge_alpha(
    const float* __restrict__ q_all, const float* __restrict__ kk,
    const int* __restrict__ edge_ui, const int* __restrict__ edge_iu,
    const float* __restrict__ p_ui, const float* __restrict__ p_iu,
    float* __restrict__ alpha, unsigned* __restrict__ amax)
{
    const int wid  = (blockIdx.x * blockDim.x + threadIdx.x) >> 6;
    const int lane = threadIdx.x & 63;
    const int nw   = (gridDim.x * blockDim.x) >> 6;
    const int h    = lane >> 4;
    const float rsd = 0.17677669529663687f;   // 1/sqrt(32)
    for (int e = wid; e < E_TOT; e += nw) {
        int src, dst; float p;
        if (e < E_PER_) {
            src = edge_ui[e];
            dst = edge_ui[E_PER_ + e] + N_USERS;
            p = p_ui[h];
        } else {
            int e2 = e - E_PER_;
            src = N_USERS + edge_iu[e2];
            dst = edge_iu[E_PER_ + e2];
            p = p_iu[h];
        }
        float2 q2 = *reinterpret_cast<const float2*>(q_all + (size_t)dst * FDIM + lane * 2);
        float2 k2 = *reinterpret_cast<const float2*>(kk    + (size_t)src * FDIM + lane * 2);
        float s = q2.x * k2.x + q2.y * k2.y;
        s += __shfl_xor(s, 1); s += __shfl_xor(s, 2);
        s += __shfl_xor(s, 4); s += __shfl_xor(s, 8);
        float al = s * p * rsd;
        if ((lane & 15) == 0) {
            alpha[(size_t)e * 4 + h] = al;
            atomicMax(amax + (size_t)dst * 4 + h, f32_enc(al));
        }
    }
}

// ---------------------------------------------------------------------------
// Kernel 4: wave per edge — w = exp(alpha - amax[dst]); atomically accumulate
// denom[dst,h] += w and outacc[dst,:] += w * vv[src,:]  (unnormalized).
// ---------------------------------------------------------------------------
__global__ __launch_bounds__(256) void edge_acc(
    const float* __restrict__ vv,
    const int* __restrict__ edge_ui, const int* __restrict__ edge_iu,
    const float* __restrict__ alpha, const unsigned* __restrict__ amax,
    float* __restrict__ denom, float* __restrict__ outacc)
{
    const int wid  = (blockIdx.x * blockDim.x + threadIdx.x) >> 6;
    const int lane = threadIdx.x & 63;
    const int nw   = (gridDim.x * blockDim.x) >> 6;
    const int h    = lane >> 4;
    for (int e = wid; e < E_TOT; e += nw) {
        int src, dst;
        if (e < E_PER_) {
            src = edge_ui[e];
            dst = edge_ui[E_PER_ + e] + N_USERS;
        } else {
            int e2 = e - E_PER_;
            src = N_USERS + edge_iu[e2];
            dst = edge_iu[E_PER_ + e2];
        }
        float al = alpha[(size_t)e * 4 + h];
        float m  = f32_dec(amax[(size_t)dst * 4 + h]);
        float w  = expf(al - m);
        if ((lane & 15) == 0) atomicAdd(denom + (size_t)dst * 4 + h, w);
        float2 v2 = *reinterpret_cast<const float2*>(vv + (size_t)src * FDIM + lane * 2);
        atomicAdd(outacc + (size_t)dst * FDIM + lane * 2,     v2.x * w);
        atomicAdd(outacc + (size_t)dst * FDIM + lane * 2 + 1, v2.y * w);
    }
}

// ---------------------------------------------------------------------------
// Kernel 5: out = sigmoid(skip)*(gelu(outacc/denom) @ Wo + bo) + (1-s)*x
// BM=32, 256 threads, 4x4 micro; Wo (64KB) fully in LDS.
// ---------------------------------------------------------------------------
__global__ __launch_bounds__(256) void final_kernel(
    const float* __restrict__ outacc, const float* __restrict__ denom,
    const float* __restrict__ x,
    const float* __restrict__ Wo, const float* __restrict__ bo,
    const float* __restrict__ skip,
    float* __restrict__ out, int M)
{
    __shared__ float Ws[128][128];
    __shared__ float Gs[128][32];    // transposed [k][r]
    const int t = threadIdx.x;
    const int m0 = blockIdx.x * 32;

    #pragma unroll
    for (int j = 0; j < 16; ++j) {
        int idx = t + j * 256;
        int row = idx >> 5, cp = idx & 31;
        *reinterpret_cast<float4*>(&Ws[row][cp * 4]) =
            *reinterpret_cast<const float4*>(Wo + (size_t)row * FDIM + cp * 4);
    }
    #pragma unroll
    for (int j = 0; j < 4; ++j) {
        int idx = t + j * 256;
        int r = idx & 31, cp = idx >> 5;
        int row = m0 + r;
        float4 v = make_float4(0.f, 0.f, 0.f, 0.f);
        if (row < M) {
            v = *reinterpret_cast<const float4*>(outacc + (size_t)row * FDIM + cp * 4);
            int hh = cp >> 3;
            float inv = 1.0f / (denom[(size_t)row * 4 + hh] + 1e-16f);
            v.x = gelu_exact(v.x * inv); v.y = gelu_exact(v.y * inv);
            v.z = gelu_exact(v.z * inv); v.w = gelu_exact(v.w * inv);
        }
        Gs[cp * 4 + 0][r] = v.x; Gs[cp * 4 + 1][r] = v.y;
        Gs[cp * 4 + 2][r] = v.z; Gs[cp * 4 + 3][r] = v.w;
    }
    __syncthreads();

    const int ty = t >> 5, tx = t & 31;
    const int r0 = ty * 4, c0 = tx * 4;
    float acc[4][4] = {};
    for (int k = 0; k < 128; ++k) {
        float4 a4 = *reinterpret_cast<const float4*>(&Gs[k][r0]);
        float4 b4 = *reinterpret_cast<const float4*>(&Ws[k][c0]);
        float a[4] = {a4.x, a4.y, a4.z, a4.w};
        float bb[4] = {b4.x, b4.y, b4.z, b4.w};
        #pragma unroll
        for (int i = 0; i < 4; ++i)
            #pragma unroll
            for (int j = 0; j < 4; ++j)
                acc[i][j] = fmaf(a[i], bb[j], acc[i][j]);
    }

    const float sg = 1.0f / (1.0f + expf(-skip[0]));
    float bv[4] = {bo[c0], bo[c0 + 1], bo[c0 + 2], bo[c0 + 3]};
    for (int i = 0; i < 4; ++i) {
        int row = m0 + r0 + i;
        if (row >= M) break;
        float4 xv = *reinterpret_cast<const float4*>(x + (size_t)row * FDIM + c0);
        float4 res;
        res.x = sg * (acc[i][0] + bv[0]) + (1.f - sg) * xv.x;
        res.y = sg * (acc[i][1] + bv[1]) + (1.f - sg) * xv.y;
        res.z = sg * (acc[i][2] + bv[2]) + (1.f - sg) * xv.z;
        res.w = sg * (acc[i][3] + bv[3]) + (1.f - sg) * xv.w;
        *reinterpret_cast<float4*>(out + (size_t)row * FDIM + c0) = res;
    }
}

// ---------------------------------------------------------------------------
extern "C" void kernel_launch(void* const* d_in, const int* in_sizes, int n_in,
                              void* d_out, int out_size, void* d_ws, size_t ws_size,
                              hipStream_t stream)
{
    const float* x_user     = (const float*)d_in[0];
    const float* x_item     = (const float*)d_in[1];
    const float* W_kqv_user = (const float*)d_in[2];
    const float* b_kqv_user = (const float*)d_in[3];
    const float* W_kqv_item = (const float*)d_in[4];
    const float* b_kqv_item = (const float*)d_in[5];
    const float* Wk_rel     = (const float*)d_in[6];
    const float* Wv_rel     = (const float*)d_in[7];
    const float* W_out_user = (const float*)d_in[8];
    const float* b_out_user = (const float*)d_in[9];
    const float* W_out_item = (const float*)d_in[10];
    const float* b_out_item = (const float*)d_in[11];
    const float* skip_user  = (const float*)d_in[12];
    const float* skip_item  = (const float*)d_in[13];
    const float* p_ui       = (const float*)d_in[14];
    const float* p_iu       = (const float*)d_in[15];
    const int*   edge_ui    = (const int*)d_in[16];
    const int*   edge_iu    = (const int*)d_in[17];

    const size_t NODE_F = (size_t)NN * FDIM;     // 12.8M floats
    float* ws     = (float*)d_ws;
    float* q_all  = ws;                          // 51.2 MB
    float* kk     = ws + NODE_F;                 // 51.2 MB
    float* vv     = ws + 2 * NODE_F;             // 51.2 MB
    float* k_raw  = ws + 3 * NODE_F;             // 51.2 MB, reused as outacc
    float* outacc = k_raw;
    float* v_raw  = ws + 4 * NODE_F;             // 51.2 MB, reused as alpha
    float* alpha  = v_raw;
    unsigned* amax = (unsigned*)(ws + 5 * NODE_F);   // 1.6 MB
    float* denom   = ws + 5 * NODE_F + (size_t)NN * NH; // 1.6 MB

    dim3 g1((N_USERS + 127) / 128, 3);
    kqv_gemm<<<g1, 256, 0, stream>>>(x_user, W_kqv_user, b_kqv_user,
                                     q_all, k_raw, v_raw, N_USERS, 0);
    kqv_gemm<<<g1, 256, 0, stream>>>(x_item, W_kqv_item, b_kqv_item,
                                     q_all, k_raw, v_raw, N_ITEMS, N_USERS);

    rel_kernel<<<NN / 8, 256, 0, stream>>>(k_raw, v_raw, Wk_rel, Wv_rel, kk, vv);

    hipMemsetAsync(amax,  0, (size_t)NN * NH * 4, stream);
    hipMemsetAsync(denom, 0, (size_t)NN * NH * 4, stream);
    hipMemsetAsync(outacc, 0, NODE_F * 4, stream);

    edge_alpha<<<2048, 256, 0, stream>>>(q_all, kk, edge_ui, edge_iu,
                                         p_ui, p_iu, alpha, amax);
    edge_acc<<<2048, 256, 0, stream>>>(vv, edge_ui, edge_iu, alpha, amax,
                                       denom, outacc);

    final_kernel<<<(N_USERS + 31) / 32, 256, 0, stream>>>(
        outacc, denom, x_user, W_out_user, b_out_user, skip_user,
        (float*)d_out, N_USERS);
    final_kernel<<<(N_ITEMS + 31) / 32, 256, 0, stream>>>(
        outacc + (size_t)N_USERS * FDIM, denom + (size_t)N_USERS * NH,
        x_item, W_out_item, b_out_item, skip_item,
        (float*)d_out + (size_t)N_USERS * FDIM, N_ITEMS);
}

// Round 2
// 582.092 us; speedup vs baseline: 2.1200x; 2.1200x over previous
//
#include <hip/hip_runtime.h>
#include <hip/hip_bf16.h>
#include <math.h>

#define N_USERS 50000
#define N_ITEMS 50000
#define NN      100000
#define E_PER_  400000
#define E_TOT   800000
#define FDIM    128
#define NH      4
#define HD      32
#define SCAN_CHUNK 1024
#define SCAN_NB    ((NN + SCAN_CHUNK - 1) / SCAN_CHUNK)   // 98

__device__ __forceinline__ float gelu_exact(float x) {
    return 0.5f * x * (1.0f + erff(x * 0.70710678118654752f));
}

// ---------------------------------------------------------------------------
// Kernel 1: C[M,384] = X[M,128] @ W[128,384] + b  (per side), split to k/q/v.
// ---------------------------------------------------------------------------
__global__ __launch_bounds__(256) void kqv_gemm(
    const float* __restrict__ X, const float* __restrict__ W,
    const float* __restrict__ b, float* __restrict__ q_all,
    float* __restrict__ k_raw, float* __restrict__ v_raw,
    int M, int side_off)
{
    __shared__ float Xs[128][128];   // transposed: Xs[k][r]
    __shared__ float Ws[128][128];   // Ws[k][c]
    const int t = threadIdx.x;
    const int m0 = blockIdx.x * 128;
    const int n0 = blockIdx.y * 128;   // 0,128,256 -> k,q,v

    #pragma unroll
    for (int j = 0; j < 16; ++j) {
        int idx = t + j * 256;
        int r = idx & 127, cp = idx >> 7;
        float4 v = make_float4(0.f, 0.f, 0.f, 0.f);
        int row = m0 + r;
        if (row < M) v = *reinterpret_cast<const float4*>(X + (size_t)row * FDIM + cp * 4);
        Xs[cp * 4 + 0][r] = v.x; Xs[cp * 4 + 1][r] = v.y;
        Xs[cp * 4 + 2][r] = v.z; Xs[cp * 4 + 3][r] = v.w;
    }
    #pragma unroll
    for (int j = 0; j < 16; ++j) {
        int idx = t + j * 256;
        int row = idx >> 5, cp = idx & 31;
        float4 v = *reinterpret_cast<const float4*>(W + (size_t)row * 384 + n0 + cp * 4);
        *reinterpret_cast<float4*>(&Ws[row][cp * 4]) = v;
    }
    __syncthreads();

    const int ty = t >> 4, tx = t & 15;
    const int r0 = ty * 8, c0 = tx * 8;
    float acc[8][8] = {};
    for (int k = 0; k < 128; ++k) {
        float4 a0 = *reinterpret_cast<const float4*>(&Xs[k][r0]);
        float4 a1 = *reinterpret_cast<const float4*>(&Xs[k][r0 + 4]);
        float4 b0 = *reinterpret_cast<const float4*>(&Ws[k][c0]);
        float4 b1 = *reinterpret_cast<const float4*>(&Ws[k][c0 + 4]);
        float a[8] = {a0.x, a0.y, a0.z, a0.w, a1.x, a1.y, a1.z, a1.w};
        float bb[8] = {b0.x, b0.y, b0.z, b0.w, b1.x, b1.y, b1.z, b1.w};
        #pragma unroll
        for (int i = 0; i < 8; ++i)
            #pragma unroll
            for (int j = 0; j < 8; ++j)
                acc[i][j] = fmaf(a[i], bb[j], acc[i][j]);
    }

    float* dst = (blockIdx.y == 0) ? k_raw : (blockIdx.y == 1) ? q_all : v_raw;
    float bv[8];
    #pragma unroll
    for (int j = 0; j < 8; ++j) bv[j] = b[n0 + c0 + j];
    for (int i = 0; i < 8; ++i) {
        int row = m0 + r0 + i;
        if (row >= M) break;
        size_t o = (size_t)(side_off + row) * FDIM + c0;
        float4 s0, s1;
        s0.x = acc[i][0] + bv[0]; s0.y = acc[i][1] + bv[1];
        s0.z = acc[i][2] + bv[2]; s0.w = acc[i][3] + bv[3];
        s1.x = acc[i][4] + bv[4]; s1.y = acc[i][5] + bv[5];
        s1.z = acc[i][6] + bv[6]; s1.w = acc[i][7] + bv[7];
        *reinterpret_cast<float4*>(dst + o)     = s0;
        *reinterpret_cast<float4*>(dst + o + 4) = s1;
    }
}

// ---------------------------------------------------------------------------
// Kernel 2: per-head relation transform
// ---------------------------------------------------------------------------
__global__ __launch_bounds__(256) void rel_kernel(
    const float* __restrict__ k_raw, const float* __restrict__ v_raw,
    const float* __restrict__ Wk_rel, const float* __restrict__ Wv_rel,
    float* __restrict__ kk, float* __restrict__ vv)
{
    __shared__ float Wk[4][32][32];
    __shared__ float Wv[4][32][32];
    __shared__ float rowk[8][128];
    __shared__ float rowv[8][128];
    const int t = threadIdx.x;
    const int nodeBase = blockIdx.x * 8;
    const int et = (nodeBase >= N_USERS) ? 1 : 0;

    #pragma unroll
    for (int j = 0; j < 16; ++j) {
        int idx = t + j * 256;
        int h = idx >> 10, rem = idx & 1023;
        Wk[h][rem >> 5][rem & 31] = Wk_rel[(size_t)(h * 2 + et) * 1024 + rem];
        Wv[h][rem >> 5][rem & 31] = Wv_rel[(size_t)(h * 2 + et) * 1024 + rem];
    }
    #pragma unroll
    for (int j = 0; j < 4; ++j) {
        int idx = t + j * 256;
        int n = idx >> 7, c = idx & 127;
        rowk[n][c] = k_raw[(size_t)(nodeBase + n) * FDIM + c];
        rowv[n][c] = v_raw[(size_t)(nodeBase + n) * FDIM + c];
    }
    __syncthreads();

    const int which = t >> 7;        // 0 = k, 1 = v
    const int c = t & 127, h = c >> 5, e = c & 31;
    const float (*Wm)[32][32] = which ? Wv : Wk;
    const float (*rows)[128]  = which ? rowv : rowk;
    float* outp = which ? vv : kk;
    for (int n = 0; n < 8; ++n) {
        float s = 0.f;
        #pragma unroll
        for (int d = 0; d < 32; ++d)
            s = fmaf(rows[n][h * 32 + d], Wm[h][d][e], s);
        outp[(size_t)(nodeBase + n) * FDIM + c] = s;
    }
}

// ---------------------------------------------------------------------------
// CSR build: histogram -> exclusive scan (3 kernels) -> fill buckets
// ---------------------------------------------------------------------------
__device__ __forceinline__ void edge_src_dst(
    int e, const int* __restrict__ edge_ui, const int* __restrict__ edge_iu,
    int& src, int& dst)
{
    if (e < E_PER_) {
        src = edge_ui[e];
        dst = edge_ui[E_PER_ + e] + N_USERS;
    } else {
        int e2 = e - E_PER_;
        src = N_USERS + edge_iu[e2];
        dst = edge_iu[E_PER_ + e2];
    }
}

__global__ __launch_bounds__(256) void hist_kernel(
    const int* __restrict__ edge_ui, const int* __restrict__ edge_iu,
    int* __restrict__ cnt)
{
    int e = blockIdx.x * blockDim.x + threadIdx.x;
    if (e >= E_TOT) return;
    int src, dst;
    edge_src_dst(e, edge_ui, edge_iu, src, dst);
    atomicAdd(cnt + dst, 1);
}

// per-block exclusive scan of 1024-element chunks; block total -> bsum
__global__ __launch_bounds__(256) void scan1_kernel(
    const int* __restrict__ cnt, int* __restrict__ base, int* __restrict__ bsum)
{
    __shared__ int ssum[256];
    const int t = threadIdx.x;
    const int i0 = blockIdx.x * SCAN_CHUNK + t * 4;
    int v[4];
    #pragma unroll
    for (int j = 0; j < 4; ++j) v[j] = (i0 + j < NN) ? cnt[i0 + j] : 0;
    int tsum = v[0] + v[1] + v[2] + v[3];
    ssum[t] = tsum;
    __syncthreads();
    int run = tsum;
    for (int off = 1; off < 256; off <<= 1) {
        int o = (t >= off) ? ssum[t - off] : 0;
        __syncthreads();
        run += o;
        ssum[t] = run;
        __syncthreads();
    }
    int excl = run - tsum;
    int p = excl;
    #pragma unroll
    for (int j = 0; j < 4; ++j) {
        if (i0 + j < NN) base[i0 + j] = p;
        p += v[j];
    }
    if (t == 255) bsum[blockIdx.x] = run;
}

__global__ void scan2_kernel(int* __restrict__ bsum)
{
    if (threadIdx.x == 0 && blockIdx.x == 0) {
        int run = 0;
        for (int i = 0; i < SCAN_NB; ++i) {
            int v = bsum[i];
            bsum[i] = run;
            run += v;
        }
    }
}

__global__ __launch_bounds__(256) void scan3_kernel(
    int* __restrict__ base, const int* __restrict__ bsum, int* __restrict__ cursor)
{
    int i = blockIdx.x * blockDim.x + threadIdx.x;
    if (i >= NN) return;
    int b = base[i] + bsum[i >> 10];
    base[i] = b;
    cursor[i] = b;
}

__global__ __launch_bounds__(256) void fill_kernel(
    const int* __restrict__ edge_ui, const int* __restrict__ edge_iu,
    int* __restrict__ cursor, int* __restrict__ esrc)
{
    int e = blockIdx.x * blockDim.x + threadIdx.x;
    if (e >= E_TOT) return;
    int src, dst;
    edge_src_dst(e, edge_ui, edge_iu, src, dst);
    int pos = atomicAdd(cursor + dst, 1);
    esrc[pos] = src;
}

// ---------------------------------------------------------------------------
// Fused attention: one wave per destination node, online softmax in registers.
// lane -> 2 dims (float2); head h = lane>>4. Output written normalized.
// ---------------------------------------------------------------------------
__global__ __launch_bounds__(256) void attn_fused(
    const float* __restrict__ q_all, const float* __restrict__ kk,
    const float* __restrict__ vv,
    const int* __restrict__ base, const int* __restrict__ cnt,
    const int* __restrict__ esrc,
    const float* __restrict__ p_ui, const float* __restrict__ p_iu,
    float* __restrict__ outacc)
{
    const int wid  = (blockIdx.x * blockDim.x + threadIdx.x) >> 6;
    const int lane = threadIdx.x & 63;
    const int nw   = (gridDim.x * blockDim.x) >> 6;
    const int h    = lane >> 4;
    const float rsd = 0.17677669529663687f;   // 1/sqrt(32)

    for (int n = wid; n < NN; n += nw) {
        const float p = (n >= N_USERS) ? p_ui[h] : p_iu[h];
        float2 q2 = *reinterpret_cast<const float2*>(q_all + (size_t)n * FDIM + lane * 2);
        float m = -INFINITY, l = 0.f;
        float2 acc = make_float2(0.f, 0.f);
        const int s0 = base[n], c = cnt[n];
        for (int j = 0; j < c; ++j) {
            int src = esrc[s0 + j];
            float2 k2 = *reinterpret_cast<const float2*>(kk + (size_t)src * FDIM + lane * 2);
            float2 v2 = *reinterpret_cast<const float2*>(vv + (size_t)src * FDIM + lane * 2);
            float s = q2.x * k2.x + q2.y * k2.y;
            s += __shfl_xor(s, 1); s += __shfl_xor(s, 2);
            s += __shfl_xor(s, 4); s += __shfl_xor(s, 8);
            float al = s * p * rsd;
            float nm = fmaxf(m, al);
            float scale = __expf(m - nm);     // first iter: exp(-inf)=0
            float w = __expf(al - nm);
            l = l * scale + w;
            acc.x = acc.x * scale + w * v2.x;
            acc.y = acc.y * scale + w * v2.y;
            m = nm;
        }
        float inv = 1.0f / (l + 1e-16f);
        float2 o = make_float2(acc.x * inv, acc.y * inv);
        *reinterpret_cast<float2*>(outacc + (size_t)n * FDIM + lane * 2) = o;
    }
}

// ---------------------------------------------------------------------------
// Kernel 5: out = sigmoid(skip)*(gelu(attn_out) @ Wo + bo) + (1-s)*x
// ---------------------------------------------------------------------------
__global__ __launch_bounds__(256) void final_kernel(
    const float* __restrict__ outacc, const float* __restrict__ x,
    const float* __restrict__ Wo, const float* __restrict__ bo,
    const float* __restrict__ skip,
    float* __restrict__ out, int M)
{
    __shared__ float Ws[128][128];
    __shared__ float Gs[128][32];    // transposed [k][r]
    const int t = threadIdx.x;
    const int m0 = blockIdx.x * 32;

    #pragma unroll
    for (int j = 0; j < 16; ++j) {
        int idx = t + j * 256;
        int row = idx >> 5, cp = idx & 31;
        *reinterpret_cast<float4*>(&Ws[row][cp * 4]) =
            *reinterpret_cast<const float4*>(Wo + (size_t)row * FDIM + cp * 4);
    }
    #pragma unroll
    for (int j = 0; j < 4; ++j) {
        int idx = t + j * 256;
        int r = idx & 31, cp = idx >> 5;
        int row = m0 + r;
        float4 v = make_float4(0.f, 0.f, 0.f, 0.f);
        if (row < M) {
            v = *reinterpret_cast<const float4*>(outacc + (size_t)row * FDIM + cp * 4);
            v.x = gelu_exact(v.x); v.y = gelu_exact(v.y);
            v.z = gelu_exact(v.z); v.w = gelu_exact(v.w);
        }
        Gs[cp * 4 + 0][r] = v.x; Gs[cp * 4 + 1][r] = v.y;
        Gs[cp * 4 + 2][r] = v.z; Gs[cp * 4 + 3][r] = v.w;
    }
    __syncthreads();

    const int ty = t >> 5, tx = t & 31;
    const int r0 = ty * 4, c0 = tx * 4;
    float acc[4][4] = {};
    for (int k = 0; k < 128; ++k) {
        float4 a4 = *reinterpret_cast<const float4*>(&Gs[k][r0]);
        float4 b4 = *reinterpret_cast<const float4*>(&Ws[k][c0]);
        float a[4] = {a4.x, a4.y, a4.z, a4.w};
        float bb[4] = {b4.x, b4.y, b4.z, b4.w};
        #pragma unroll
        for (int i = 0; i < 4; ++i)
            #pragma unroll
            for (int j = 0; j < 4; ++j)
                acc[i][j] = fmaf(a[i], bb[j], acc[i][j]);
    }

    const float sg = 1.0f / (1.0f + expf(-skip[0]));
    float bv[4] = {bo[c0], bo[c0 + 1], bo[c0 + 2], bo[c0 + 3]};
    for (int i = 0; i < 4; ++i) {
        int row = m0 + r0 + i;
        if (row >= M) break;
        float4 xv = *reinterpret_cast<const float4*>(x + (size_t)row * FDIM + c0);
        float4 res;
        res.x = sg * (acc[i][0] + bv[0]) + (1.f - sg) * xv.x;
        res.y = sg * (acc[i][1] + bv[1]) + (1.f - sg) * xv.y;
        res.z = sg * (acc[i][2] + bv[2]) + (1.f - sg) * xv.z;
        res.w = sg * (acc[i][3] + bv[3]) + (1.f - sg) * xv.w;
        *reinterpret_cast<float4*>(out + (size_t)row * FDIM + c0) = res;
    }
}

// ---------------------------------------------------------------------------
extern "C" void kernel_launch(void* const* d_in, const int* in_sizes, int n_in,
                              void* d_out, int out_size, void* d_ws, size_t ws_size,
                              hipStream_t stream)
{
    const float* x_user     = (const float*)d_in[0];
    const float* x_item     = (const float*)d_in[1];
    const float* W_kqv_user = (const float*)d_in[2];
    const float* b_kqv_user = (const float*)d_in[3];
    const float* W_kqv_item = (const float*)d_in[4];
    const float* b_kqv_item = (const float*)d_in[5];
    const float* Wk_rel     = (const float*)d_in[6];
    const float* Wv_rel     = (const float*)d_in[7];
    const float* W_out_user = (const float*)d_in[8];
    const float* b_out_user = (const float*)d_in[9];
    const float* W_out_item = (const float*)d_in[10];
    const float* b_out_item = (const float*)d_in[11];
    const float* skip_user  = (const float*)d_in[12];
    const float* skip_item  = (const float*)d_in[13];
    const float* p_ui       = (const float*)d_in[14];
    const float* p_iu       = (const float*)d_in[15];
    const int*   edge_ui    = (const int*)d_in[16];
    const int*   edge_iu    = (const int*)d_in[17];

    const size_t NODE_F = (size_t)NN * FDIM;     // 12.8M floats
    float* ws     = (float*)d_ws;
    float* q_all  = ws;                          // 51.2 MB
    float* kk     = ws + NODE_F;
    float* vv     = ws + 2 * NODE_F;
    float* k_raw  = ws + 3 * NODE_F;             // reused as outacc (attn output)
    float* outacc = k_raw;
    float* v_raw  = ws + 4 * NODE_F;             // reused as esrc after rel_kernel
    int*   esrc   = (int*)v_raw;
    int*   ip     = (int*)(ws + 5 * NODE_F);
    int*   cnt    = ip;                          // NN
    int*   base   = ip + NN;                     // NN
    int*   cursor = ip + 2 * NN;                 // NN
    int*   bsum   = ip + 3 * NN;                 // SCAN_NB

    dim3 g1((N_USERS + 127) / 128, 3);
    kqv_gemm<<<g1, 256, 0, stream>>>(x_user, W_kqv_user, b_kqv_user,
                                     q_all, k_raw, v_raw, N_USERS, 0);
    kqv_gemm<<<g1, 256, 0, stream>>>(x_item, W_kqv_item, b_kqv_item,
                                     q_all, k_raw, v_raw, N_ITEMS, N_USERS);

    rel_kernel<<<NN / 8, 256, 0, stream>>>(k_raw, v_raw, Wk_rel, Wv_rel, kk, vv);

    // ---- CSR build (esrc overlays v_raw => must run after rel_kernel) ----
    hipMemsetAsync(cnt, 0, (size_t)NN * 4, stream);
    hist_kernel<<<(E_TOT + 255) / 256, 256, 0, stream>>>(edge_ui, edge_iu, cnt);
    scan1_kernel<<<SCAN_NB, 256, 0, stream>>>(cnt, base, bsum);
    scan2_kernel<<<1, 64, 0, stream>>>(bsum);
    scan3_kernel<<<(NN + 255) / 256, 256, 0, stream>>>(base, bsum, cursor);
    fill_kernel<<<(E_TOT + 255) / 256, 256, 0, stream>>>(edge_ui, edge_iu, cursor, esrc);

    attn_fused<<<2048, 256, 0, stream>>>(q_all, kk, vv, base, cnt, esrc,
                                         p_ui, p_iu, outacc);

    final_kernel<<<(N_USERS + 31) / 32, 256, 0, stream>>>(
        outacc, x_user, W_out_user, b_out_user, skip_user,
        (float*)d_out, N_USERS);
    final_kernel<<<(N_ITEMS + 31) / 32, 256, 0, stream>>>(
        outacc + (size_t)N_USERS * FDIM, x_item, W_out_item, b_out_item, skip_item,
        (float*)d_out + (size_t)N_USERS * FDIM, N_ITEMS);
}

// Round 3
// 365.042 us; speedup vs baseline: 3.3806x; 1.5946x over previous
//
#include <hip/hip_runtime.h>
#include <hip/hip_bf16.h>
#include <math.h>

#define N_USERS 50000
#define N_ITEMS 50000
#define NN      100000
#define E_PER_  400000
#define E_TOT   800000
#define FDIM    128
#define NH      4
#define HD      32
#define SCAN_CHUNK 1024
#define SCAN_NB    ((NN + SCAN_CHUNK - 1) / SCAN_CHUNK)   // 98

typedef __attribute__((ext_vector_type(8))) short bfrag;   // 8 bf16 (4 VGPR)
typedef __attribute__((ext_vector_type(4))) float f32x4;

__device__ __forceinline__ float gelu_exact(float x) {
    return 0.5f * x * (1.0f + erff(x * 0.70710678118654752f));
}
__device__ __forceinline__ unsigned short f2bf(float f) {
    unsigned u = __float_as_uint(f);
    unsigned r = u + 0x7fffu + ((u >> 16) & 1u);
    return (unsigned short)(r >> 16);
}
__device__ __forceinline__ float bf2f(unsigned short s) {
    return __uint_as_float((unsigned)s << 16);
}

// ---------------------------------------------------------------------------
// Weight prep: fuse rel-transform into KQV weights, output transposed bf16
// Wt[n][k] (n=0..383 -> kk(0:128), q(128:256), vv(256:384)), fused f32 bias.
// ---------------------------------------------------------------------------
__global__ void prep_kqv(
    const float* __restrict__ W, const float* __restrict__ b,
    const float* __restrict__ Wk_rel, const float* __restrict__ Wv_rel,
    int et, unsigned short* __restrict__ Wt, float* __restrict__ bias_f)
{
    const int n = blockIdx.x;      // 0..383
    const int k = threadIdx.x;     // 0..127
    float s;
    if (n < 128) {
        int h = n >> 5, e = n & 31;
        const float* wr = Wk_rel + (size_t)(h * 2 + et) * 1024 + e;
        const float* wc = W + (size_t)k * 384 + h * 32;
        s = 0.f;
        for (int d = 0; d < 32; ++d) s = fmaf(wc[d], wr[d * 32], s);
        if (k == 0) {
            float bs = 0.f;
            for (int d = 0; d < 32; ++d) bs = fmaf(b[h * 32 + d], wr[d * 32], bs);
            bias_f[n] = bs;
        }
    } else if (n < 256) {
        s = W[(size_t)k * 384 + n];
        if (k == 0) bias_f[n] = b[n];
    } else {
        int h = (n - 256) >> 5, e = (n - 256) & 31;
        const float* wr = Wv_rel + (size_t)(h * 2 + et) * 1024 + e;
        const float* wc = W + (size_t)k * 384 + 256 + h * 32;
        s = 0.f;
        for (int d = 0; d < 32; ++d) s = fmaf(wc[d], wr[d * 32], s);
        if (k == 0) {
            float bs = 0.f;
            for (int d = 0; d < 32; ++d) bs = fmaf(b[256 + h * 32 + d], wr[d * 32], bs);
            bias_f[n] = bs;
        }
    }
    Wt[(size_t)n * 128 + k] = f2bf(s);
}

__global__ void prep_wo(const float* __restrict__ W, unsigned short* __restrict__ Wt)
{
    int i = blockIdx.x * blockDim.x + threadIdx.x;
    if (i >= 128 * 128) return;
    int nrow = i >> 7, k = i & 127;
    Wt[i] = f2bf(W[(size_t)k * 128 + nrow]);
}

// ---------------------------------------------------------------------------
// KQV GEMM: out[row][0:384] = x[row][0:128] @ Wt^T + bias, bf16 MFMA 16x16x32.
// BM=64, N split in two 192-col halves (LDS 48KB W + 16KB X = 64KB).
// XOR-swizzle ((row&7)<<4) on LDS byte addr, both write and read sides.
// ---------------------------------------------------------------------------
__global__ __launch_bounds__(256, 2) void kqv_mfma(
    const float* __restrict__ X,
    const unsigned short* __restrict__ Wt,   // [384][128] bf16
    const float* __restrict__ bias,          // [384] f32
    unsigned short* __restrict__ kk_b,
    unsigned short* __restrict__ q_b,
    unsigned short* __restrict__ vv_b,
    int M, int side_off)
{
    __shared__ unsigned short Ws[192 * 128];  // 48KB, current half of W
    __shared__ unsigned short Xs[64 * 128];   // 16KB
    const int t = threadIdx.x;
    const int m0 = blockIdx.x * 64;

    // stage X (f32 -> bf16, swizzled)
    for (int c = t; c < 64 * 16; c += 256) {
        int r = c >> 4, sub = c & 15;
        int row = m0 + r;
        float4 a = make_float4(0.f, 0.f, 0.f, 0.f);
        float4 b4 = make_float4(0.f, 0.f, 0.f, 0.f);
        if (row < M) {
            a  = *reinterpret_cast<const float4*>(X + (size_t)row * 128 + sub * 8);
            b4 = *reinterpret_cast<const float4*>(X + (size_t)row * 128 + sub * 8 + 4);
        }
        uint4 pk;
        pk.x = (unsigned)f2bf(a.x)  | ((unsigned)f2bf(a.y)  << 16);
        pk.y = (unsigned)f2bf(a.z)  | ((unsigned)f2bf(a.w)  << 16);
        pk.z = (unsigned)f2bf(b4.x) | ((unsigned)f2bf(b4.y) << 16);
        pk.w = (unsigned)f2bf(b4.z) | ((unsigned)f2bf(b4.w) << 16);
        int dst = r * 256 + ((sub * 16) ^ ((r & 7) << 4));
        *reinterpret_cast<uint4*>(reinterpret_cast<char*>(Xs) + dst) = pk;
    }

    const int wave = t >> 6, lane = t & 63;
    const int lr = lane & 15, lg = lane >> 4;
    bfrag am[4][4];
    bool amLoaded = false;

    #pragma unroll
    for (int half = 0; half < 2; ++half) {
        __syncthreads();   // Xs ready (1st) / prev-half reads done (2nd)
        // stage this half of W (bf16 copy, swizzled): rows half*192 .. +192
        for (int c = t; c < 192 * 16; c += 256) {
            int r = c >> 4, sub = c & 15;
            uint4 v = *reinterpret_cast<const uint4*>(
                reinterpret_cast<const char*>(Wt) + (size_t)(half * 192 + r) * 256 + sub * 16);
            int dst = r * 256 + ((sub * 16) ^ ((r & 7) << 4));
            *reinterpret_cast<uint4*>(reinterpret_cast<char*>(Ws) + dst) = v;
        }
        __syncthreads();

        if (!amLoaded) {
            amLoaded = true;
            #pragma unroll
            for (int mt = 0; mt < 4; ++mt)
                #pragma unroll
                for (int ks = 0; ks < 4; ++ks) {
                    int row = mt * 16 + lr;
                    int off = row * 256 + ((ks * 64 + lg * 16) ^ ((row & 7) << 4));
                    am[mt][ks] = *reinterpret_cast<const bfrag*>(
                        reinterpret_cast<const char*>(Xs) + off);
                }
        }

        f32x4 acc[4][3];
        const f32x4 zero = {0.f, 0.f, 0.f, 0.f};
        #pragma unroll
        for (int mt = 0; mt < 4; ++mt)
            #pragma unroll
            for (int nt = 0; nt < 3; ++nt) acc[mt][nt] = zero;

        #pragma unroll
        for (int nt = 0; nt < 3; ++nt) {
            bfrag bt[4];
            int row = wave * 48 + nt * 16 + lr;   // row within this half's 192
            #pragma unroll
            for (int ks = 0; ks < 4; ++ks) {
                int off = row * 256 + ((ks * 64 + lg * 16) ^ ((row & 7) << 4));
                bt[ks] = *reinterpret_cast<const bfrag*>(
                    reinterpret_cast<const char*>(Ws) + off);
            }
            #pragma unroll
            for (int mt = 0; mt < 4; ++mt)
                #pragma unroll
                for (int ks = 0; ks < 4; ++ks)
                    acc[mt][nt] = __builtin_amdgcn_mfma_f32_16x16x32_bf16(
                        am[mt][ks], bt[ks], acc[mt][nt], 0, 0, 0);
        }

        // epilogue for this half: C[row][g], row=(lg*4+r), col=lr per C/D layout
        #pragma unroll
        for (int nt = 0; nt < 3; ++nt) {
            int g = half * 192 + wave * 48 + nt * 16 + lr;   // global out col
            float bv = bias[g];
            unsigned short* arr; int ic;
            if (g < 128)      { arr = kk_b; ic = g; }
            else if (g < 256) { arr = q_b;  ic = g - 128; }
            else              { arr = vv_b; ic = g - 256; }
            #pragma unroll
            for (int mt = 0; mt < 4; ++mt)
                #pragma unroll
                for (int r = 0; r < 4; ++r) {
                    int row = m0 + mt * 16 + lg * 4 + r;
                    if (row < M)
                        arr[(size_t)(side_off + row) * 128 + ic] = f2bf(acc[mt][nt][r] + bv);
                }
        }
    }
}

// ---------------------------------------------------------------------------
// CSR build: histogram -> exclusive scan -> fill buckets
// ---------------------------------------------------------------------------
__device__ __forceinline__ void edge_src_dst(
    int e, const int* __restrict__ edge_ui, const int* __restrict__ edge_iu,
    int& src, int& dst)
{
    if (e < E_PER_) {
        src = edge_ui[e];
        dst = edge_ui[E_PER_ + e] + N_USERS;
    } else {
        int e2 = e - E_PER_;
        src = N_USERS + edge_iu[e2];
        dst = edge_iu[E_PER_ + e2];
    }
}

__global__ __launch_bounds__(256) void hist_kernel(
    const int* __restrict__ edge_ui, const int* __restrict__ edge_iu,
    int* __restrict__ cnt)
{
    int e = blockIdx.x * blockDim.x + threadIdx.x;
    if (e >= E_TOT) return;
    int src, dst;
    edge_src_dst(e, edge_ui, edge_iu, src, dst);
    atomicAdd(cnt + dst, 1);
}

__global__ __launch_bounds__(256) void scan1_kernel(
    const int* __restrict__ cnt, int* __restrict__ base, int* __restrict__ bsum)
{
    __shared__ int ssum[256];
    const int t = threadIdx.x;
    const int i0 = blockIdx.x * SCAN_CHUNK + t * 4;
    int v[4];
    #pragma unroll
    for (int j = 0; j < 4; ++j) v[j] = (i0 + j < NN) ? cnt[i0 + j] : 0;
    int tsum = v[0] + v[1] + v[2] + v[3];
    ssum[t] = tsum;
    __syncthreads();
    int run = tsum;
    for (int off = 1; off < 256; off <<= 1) {
        int o = (t >= off) ? ssum[t - off] : 0;
        __syncthreads();
        run += o;
        ssum[t] = run;
        __syncthreads();
    }
    int excl = run - tsum;
    int p = excl;
    #pragma unroll
    for (int j = 0; j < 4; ++j) {
        if (i0 + j < NN) base[i0 + j] = p;
        p += v[j];
    }
    if (t == 255) bsum[blockIdx.x] = run;
}

__global__ void scan2_kernel(int* __restrict__ bsum)
{
    if (threadIdx.x == 0 && blockIdx.x == 0) {
        int run = 0;
        for (int i = 0; i < SCAN_NB; ++i) {
            int v = bsum[i];
            bsum[i] = run;
            run += v;
        }
    }
}

__global__ __launch_bounds__(256) void scan3_kernel(
    int* __restrict__ base, const int* __restrict__ bsum, int* __restrict__ cursor)
{
    int i = blockIdx.x * blockDim.x + threadIdx.x;
    if (i >= NN) return;
    int b = base[i] + bsum[i >> 10];
    base[i] = b;
    cursor[i] = b;
}

__global__ __launch_bounds__(256) void fill_kernel(
    const int* __restrict__ edge_ui, const int* __restrict__ edge_iu,
    int* __restrict__ cursor, int* __restrict__ esrc)
{
    int e = blockIdx.x * blockDim.x + threadIdx.x;
    if (e >= E_TOT) return;
    int src, dst;
    edge_src_dst(e, edge_ui, edge_iu, src, dst);
    int pos = atomicAdd(cursor + dst, 1);
    esrc[pos] = src;
}

// ---------------------------------------------------------------------------
// Fused attention: one wave per destination node, online softmax, bf16 I/O.
// ---------------------------------------------------------------------------
__global__ __launch_bounds__(256) void attn_fused(
    const unsigned short* __restrict__ q_b, const unsigned short* __restrict__ kk_b,
    const unsigned short* __restrict__ vv_b,
    const int* __restrict__ base, const int* __restrict__ cnt,
    const int* __restrict__ esrc,
    const float* __restrict__ p_ui, const float* __restrict__ p_iu,
    unsigned short* __restrict__ oa)
{
    const int wid  = (blockIdx.x * blockDim.x + threadIdx.x) >> 6;
    const int lane = threadIdx.x & 63;
    const int nw   = (gridDim.x * blockDim.x) >> 6;
    const int h    = lane >> 4;
    const float rsd = 0.17677669529663687f;   // 1/sqrt(32)

    for (int n = wid; n < NN; n += nw) {
        const float p = (n >= N_USERS) ? p_ui[h] : p_iu[h];
        unsigned qu = *reinterpret_cast<const unsigned*>(q_b + (size_t)n * FDIM + lane * 2);
        float qx = __uint_as_float(qu << 16);
        float qy = __uint_as_float(qu & 0xffff0000u);
        float m = -INFINITY, l = 0.f;
        float accx = 0.f, accy = 0.f;
        const int s0 = base[n], c = cnt[n];
        for (int j = 0; j < c; ++j) {
            int src = esrc[s0 + j];
            unsigned ku = *reinterpret_cast<const unsigned*>(kk_b + (size_t)src * FDIM + lane * 2);
            unsigned vu = *reinterpret_cast<const unsigned*>(vv_b + (size_t)src * FDIM + lane * 2);
            float s = qx * __uint_as_float(ku << 16) + qy * __uint_as_float(ku & 0xffff0000u);
            s += __shfl_xor(s, 1); s += __shfl_xor(s, 2);
            s += __shfl_xor(s, 4); s += __shfl_xor(s, 8);
            float al = s * p * rsd;
            float nm = fmaxf(m, al);
            float scale = __expf(m - nm);
            float w = __expf(al - nm);
            l = l * scale + w;
            accx = accx * scale + w * __uint_as_float(vu << 16);
            accy = accy * scale + w * __uint_as_float(vu & 0xffff0000u);
            m = nm;
        }
        float inv = 1.0f / (l + 1e-16f);
        unsigned pk = (unsigned)f2bf(accx * inv) | ((unsigned)f2bf(accy * inv) << 16);
        *reinterpret_cast<unsigned*>(oa + (size_t)n * FDIM + lane * 2) = pk;
    }
}

// ---------------------------------------------------------------------------
// Final: out = sg*(gelu(oa) @ Wo + bo) + (1-sg)*x, bf16 MFMA, f32 out.
// BM=64, N=128. LDS: Wo 32KB + G 16KB, both XOR-swizzled.
// ---------------------------------------------------------------------------
__global__ __launch_bounds__(256, 2) void final_mfma(
    const unsigned short* __restrict__ oa,   // [M][128] bf16 (this side)
    const float* __restrict__ x,
    const unsigned short* __restrict__ Wt,   // [128][128] bf16 (n,k)
    const float* __restrict__ bo,
    const float* __restrict__ skip,
    float* __restrict__ out, int M)
{
    __shared__ unsigned short Ws[128 * 128];  // 32KB
    __shared__ unsigned short Gs[64 * 128];   // 16KB
    const int t = threadIdx.x;
    const int m0 = blockIdx.x * 64;

    for (int c = t; c < 128 * 16; c += 256) {
        int r = c >> 4, sub = c & 15;
        uint4 v = *reinterpret_cast<const uint4*>(
            reinterpret_cast<const char*>(Wt) + r * 256 + sub * 16);
        int dst = r * 256 + ((sub * 16) ^ ((r & 7) << 4));
        *reinterpret_cast<uint4*>(reinterpret_cast<char*>(Ws) + dst) = v;
    }
    for (int c = t; c < 64 * 16; c += 256) {
        int r = c >> 4, sub = c & 15;
        int row = m0 + r;
        uint4 pk = make_uint4(0u, 0u, 0u, 0u);
        if (row < M) {
            uint4 v = *reinterpret_cast<const uint4*>(
                reinterpret_cast<const char*>(oa) + (size_t)row * 256 + sub * 16);
            unsigned q[4] = {v.x, v.y, v.z, v.w};
            unsigned o[4];
            #pragma unroll
            for (int j = 0; j < 4; ++j) {
                float lo = gelu_exact(__uint_as_float(q[j] << 16));
                float hi = gelu_exact(__uint_as_float(q[j] & 0xffff0000u));
                o[j] = (unsigned)f2bf(lo) | ((unsigned)f2bf(hi) << 16);
            }
            pk = make_uint4(o[0], o[1], o[2], o[3]);
        }
        int dst = r * 256 + ((sub * 16) ^ ((r & 7) << 4));
        *reinterpret_cast<uint4*>(reinterpret_cast<char*>(Gs) + dst) = pk;
    }
    __syncthreads();

    const int wave = t >> 6, lane = t & 63;
    const int lr = lane & 15, lg = lane >> 4;
    const int n0 = wave * 32;

    bfrag am[4][4];
    #pragma unroll
    for (int mt = 0; mt < 4; ++mt)
        #pragma unroll
        for (int ks = 0; ks < 4; ++ks) {
            int row = mt * 16 + lr;
            int off = row * 256 + ((ks * 64 + lg * 16) ^ ((row & 7) << 4));
            am[mt][ks] = *reinterpret_cast<const bfrag*>(
                reinterpret_cast<const char*>(Gs) + off);
        }

    f32x4 acc[4][2];
    const f32x4 zero = {0.f, 0.f, 0.f, 0.f};
    #pragma unroll
    for (int mt = 0; mt < 4; ++mt) { acc[mt][0] = zero; acc[mt][1] = zero; }

    #pragma unroll
    for (int nt = 0; nt < 2; ++nt) {
        bfrag bt[4];
        int row = n0 + nt * 16 + lr;
        #pragma unroll
        for (int ks = 0; ks < 4; ++ks) {
            int off = row * 256 + ((ks * 64 + lg * 16) ^ ((row & 7) << 4));
            bt[ks] = *reinterpret_cast<const bfrag*>(
                reinterpret_cast<const char*>(Ws) + off);
        }
        #pragma unroll
        for (int mt = 0; mt < 4; ++mt)
            #pragma unroll
            for (int ks = 0; ks < 4; ++ks)
                acc[mt][nt] = __builtin_amdgcn_mfma_f32_16x16x32_bf16(
                    am[mt][ks], bt[ks], acc[mt][nt], 0, 0, 0);
    }

    const float sg = 1.0f / (1.0f + expf(-skip[0]));
    #pragma unroll
    for (int nt = 0; nt < 2; ++nt) {
        int col = n0 + nt * 16 + lr;
        float bv = bo[col];
        #pragma unroll
        for (int mt = 0; mt < 4; ++mt)
            #pragma unroll
            for (int r = 0; r < 4; ++r) {
                int row = m0 + mt * 16 + lg * 4 + r;
                if (row < M) {
                    float xv = x[(size_t)row * 128 + col];
                    out[(size_t)row * 128 + col] =
                        sg * (acc[mt][nt][r] + bv) + (1.f - sg) * xv;
                }
            }
    }
}

// ---------------------------------------------------------------------------
extern "C" void kernel_launch(void* const* d_in, const int* in_sizes, int n_in,
                              void* d_out, int out_size, void* d_ws, size_t ws_size,
                              hipStream_t stream)
{
    const float* x_user     = (const float*)d_in[0];
    const float* x_item     = (const float*)d_in[1];
    const float* W_kqv_user = (const float*)d_in[2];
    const float* b_kqv_user = (const float*)d_in[3];
    const float* W_kqv_item = (const float*)d_in[4];
    const float* b_kqv_item = (const float*)d_in[5];
    const float* Wk_rel     = (const float*)d_in[6];
    const float* Wv_rel     = (const float*)d_in[7];
    const float* W_out_user = (const float*)d_in[8];
    const float* b_out_user = (const float*)d_in[9];
    const float* W_out_item = (const float*)d_in[10];
    const float* b_out_item = (const float*)d_in[11];
    const float* skip_user  = (const float*)d_in[12];
    const float* skip_item  = (const float*)d_in[13];
    const float* p_ui       = (const float*)d_in[14];
    const float* p_iu       = (const float*)d_in[15];
    const int*   edge_ui    = (const int*)d_in[16];
    const int*   edge_iu    = (const int*)d_in[17];

    const size_t NODE_F = (size_t)NN * FDIM;     // 12.8M elems
    char* w = (char*)d_ws;
    size_t off = 0;
    auto alloc = [&](size_t bytes) {
        char* p = w + off;
        off += (bytes + 255) & ~(size_t)255;
        return p;
    };
    unsigned short* q_b   = (unsigned short*)alloc(NODE_F * 2);
    unsigned short* kk_b  = (unsigned short*)alloc(NODE_F * 2);
    unsigned short* vv_b  = (unsigned short*)alloc(NODE_F * 2);
    unsigned short* oa_b  = (unsigned short*)alloc(NODE_F * 2);
    int* esrc   = (int*)alloc((size_t)E_TOT * 4);
    int* cnt    = (int*)alloc((size_t)NN * 4);
    int* base   = (int*)alloc((size_t)NN * 4);
    int* cursor = (int*)alloc((size_t)NN * 4);
    int* bsum   = (int*)alloc((size_t)SCAN_NB * 4);
    unsigned short* Wt_u   = (unsigned short*)alloc(384 * 128 * 2);
    unsigned short* Wt_i   = (unsigned short*)alloc(384 * 128 * 2);
    float*          bias_u = (float*)alloc(384 * 4);
    float*          bias_i = (float*)alloc(384 * 4);
    unsigned short* Wo_u   = (unsigned short*)alloc(128 * 128 * 2);
    unsigned short* Wo_i   = (unsigned short*)alloc(128 * 128 * 2);

    // weight prep
    prep_kqv<<<384, 128, 0, stream>>>(W_kqv_user, b_kqv_user, Wk_rel, Wv_rel, 0, Wt_u, bias_u);
    prep_kqv<<<384, 128, 0, stream>>>(W_kqv_item, b_kqv_item, Wk_rel, Wv_rel, 1, Wt_i, bias_i);
    prep_wo<<<64, 256, 0, stream>>>(W_out_user, Wo_u);
    prep_wo<<<64, 256, 0, stream>>>(W_out_item, Wo_i);

    // fused KQV(+rel) GEMM, bf16 MFMA
    const int NB = (N_USERS + 63) / 64;   // 782
    kqv_mfma<<<NB, 256, 0, stream>>>(x_user, Wt_u, bias_u, kk_b, q_b, vv_b, N_USERS, 0);
    kqv_mfma<<<NB, 256, 0, stream>>>(x_item, Wt_i, bias_i, kk_b, q_b, vv_b, N_ITEMS, N_USERS);

    // CSR build
    hipMemsetAsync(cnt, 0, (size_t)NN * 4, stream);
    hist_kernel<<<(E_TOT + 255) / 256, 256, 0, stream>>>(edge_ui, edge_iu, cnt);
    scan1_kernel<<<SCAN_NB, 256, 0, stream>>>(cnt, base, bsum);
    scan2_kernel<<<1, 64, 0, stream>>>(bsum);
    scan3_kernel<<<(NN + 255) / 256, 256, 0, stream>>>(base, bsum, cursor);
    fill_kernel<<<(E_TOT + 255) / 256, 256, 0, stream>>>(edge_ui, edge_iu, cursor, esrc);

    attn_fused<<<2048, 256, 0, stream>>>(q_b, kk_b, vv_b, base, cnt, esrc,
                                         p_ui, p_iu, oa_b);

    final_mfma<<<NB, 256, 0, stream>>>(oa_b, x_user, Wo_u, b_out_user, skip_user,
                                       (float*)d_out, N_USERS);
    final_mfma<<<NB, 256, 0, stream>>>(oa_b + (size_t)N_USERS * FDIM, x_item, Wo_i,
                                       b_out_item, skip_item,
                                       (float*)d_out + (size_t)N_USERS * FDIM, N_ITEMS);
}

// Round 4
// 293.893 us; speedup vs baseline: 4.1990x; 1.2421x over previous
//
#include <hip/hip_runtime.h>
#include <hip/hip_bf16.h>
#include <math.h>

#define N_USERS 50000
#define N_ITEMS 50000
#define NN      100000
#define E_PER_  400000
#define E_TOT   800000
#define FDIM    128
#define NH      4
#define HD      32
#define SCAN_CHUNK 1024
#define SCAN_NB    ((NN + SCAN_CHUNK - 1) / SCAN_CHUNK)   // 98

typedef __attribute__((ext_vector_type(8))) short bfrag;   // 8 bf16 (4 VGPR)
typedef __attribute__((ext_vector_type(4))) float f32x4;

__device__ __forceinline__ float gelu_exact(float x) {
    return 0.5f * x * (1.0f + erff(x * 0.70710678118654752f));
}
__device__ __forceinline__ unsigned short f2bf(float f) {
    unsigned u = __float_as_uint(f);
    unsigned r = u + 0x7fffu + ((u >> 16) & 1u);
    return (unsigned short)(r >> 16);
}
__device__ __forceinline__ void unpack8(uint4 u, float* f) {
    f[0] = __uint_as_float(u.x << 16); f[1] = __uint_as_float(u.x & 0xffff0000u);
    f[2] = __uint_as_float(u.y << 16); f[3] = __uint_as_float(u.y & 0xffff0000u);
    f[4] = __uint_as_float(u.z << 16); f[5] = __uint_as_float(u.z & 0xffff0000u);
    f[6] = __uint_as_float(u.w << 16); f[7] = __uint_as_float(u.w & 0xffff0000u);
}

// ---------------------------------------------------------------------------
// Weight prep: fuse rel-transform into KQV weights, output transposed bf16
// Wt[n][k] (n=0..383 -> kk(0:128), q(128:256), vv(256:384)), fused f32 bias.
// ---------------------------------------------------------------------------
__global__ void prep_kqv(
    const float* __restrict__ W, const float* __restrict__ b,
    const float* __restrict__ Wk_rel, const float* __restrict__ Wv_rel,
    int et, unsigned short* __restrict__ Wt, float* __restrict__ bias_f)
{
    const int n = blockIdx.x;      // 0..383
    const int k = threadIdx.x;     // 0..127
    float s;
    if (n < 128) {
        int h = n >> 5, e = n & 31;
        const float* wr = Wk_rel + (size_t)(h * 2 + et) * 1024 + e;
        const float* wc = W + (size_t)k * 384 + h * 32;
        s = 0.f;
        for (int d = 0; d < 32; ++d) s = fmaf(wc[d], wr[d * 32], s);
        if (k == 0) {
            float bs = 0.f;
            for (int d = 0; d < 32; ++d) bs = fmaf(b[h * 32 + d], wr[d * 32], bs);
            bias_f[n] = bs;
        }
    } else if (n < 256) {
        s = W[(size_t)k * 384 + n];
        if (k == 0) bias_f[n] = b[n];
    } else {
        int h = (n - 256) >> 5, e = (n - 256) & 31;
        const float* wr = Wv_rel + (size_t)(h * 2 + et) * 1024 + e;
        const float* wc = W + (size_t)k * 384 + 256 + h * 32;
        s = 0.f;
        for (int d = 0; d < 32; ++d) s = fmaf(wc[d], wr[d * 32], s);
        if (k == 0) {
            float bs = 0.f;
            for (int d = 0; d < 32; ++d) bs = fmaf(b[256 + h * 32 + d], wr[d * 32], bs);
            bias_f[n] = bs;
        }
    }
    Wt[(size_t)n * 128 + k] = f2bf(s);
}

__global__ void prep_wo(const float* __restrict__ W, unsigned short* __restrict__ Wt)
{
    int i = blockIdx.x * blockDim.x + threadIdx.x;
    if (i >= 128 * 128) return;
    int nrow = i >> 7, k = i & 127;
    Wt[i] = f2bf(W[(size_t)k * 128 + nrow]);
}

// ---------------------------------------------------------------------------
// KQV GEMM: BM=128, N in three 128-col chunks (chunk 0->kk, 1->q, 2->vv).
// LDS 64KB (Xs 32 + Ws 32), XOR-swizzled both sides.
// ---------------------------------------------------------------------------
__global__ __launch_bounds__(256, 2) void kqv_mfma(
    const float* __restrict__ X,
    const unsigned short* __restrict__ Wt,   // [384][128] bf16
    const float* __restrict__ bias,          // [384] f32
    unsigned short* __restrict__ kk_b,
    unsigned short* __restrict__ q_b,
    unsigned short* __restrict__ vv_b,
    int M, int side_off)
{
    __shared__ unsigned short Xs[128 * 128];  // 32KB
    __shared__ unsigned short Ws[128 * 128];  // 32KB
    const int t = threadIdx.x;
    const int m0 = blockIdx.x * 128;

    // stage X (f32 -> bf16, swizzled)
    for (int c = t; c < 128 * 16; c += 256) {
        int r = c >> 4, sub = c & 15;
        int row = m0 + r;
        float4 a = make_float4(0.f, 0.f, 0.f, 0.f);
        float4 b4 = make_float4(0.f, 0.f, 0.f, 0.f);
        if (row < M) {
            a  = *reinterpret_cast<const float4*>(X + (size_t)row * 128 + sub * 8);
            b4 = *reinterpret_cast<const float4*>(X + (size_t)row * 128 + sub * 8 + 4);
        }
        uint4 pk;
        pk.x = (unsigned)f2bf(a.x)  | ((unsigned)f2bf(a.y)  << 16);
        pk.y = (unsigned)f2bf(a.z)  | ((unsigned)f2bf(a.w)  << 16);
        pk.z = (unsigned)f2bf(b4.x) | ((unsigned)f2bf(b4.y) << 16);
        pk.w = (unsigned)f2bf(b4.z) | ((unsigned)f2bf(b4.w) << 16);
        int dst = r * 256 + ((sub * 16) ^ ((r & 7) << 4));
        *reinterpret_cast<uint4*>(reinterpret_cast<char*>(Xs) + dst) = pk;
    }
    // stage W chunk 0
    for (int c = t; c < 128 * 16; c += 256) {
        int r = c >> 4, sub = c & 15;
        uint4 v = *reinterpret_cast<const uint4*>(
            reinterpret_cast<const char*>(Wt) + (size_t)r * 256 + sub * 16);
        int dst = r * 256 + ((sub * 16) ^ ((r & 7) << 4));
        *reinterpret_cast<uint4*>(reinterpret_cast<char*>(Ws) + dst) = v;
    }
    __syncthreads();

    const int wave = t >> 6, lane = t & 63;
    const int lr = lane & 15, lg = lane >> 4;

    bfrag am[2][4];
    #pragma unroll
    for (int mt = 0; mt < 2; ++mt)
        #pragma unroll
        for (int ks = 0; ks < 4; ++ks) {
            int row = wave * 32 + mt * 16 + lr;
            int off = row * 256 + ((ks * 64 + lg * 16) ^ ((row & 7) << 4));
            am[mt][ks] = *reinterpret_cast<const bfrag*>(
                reinterpret_cast<const char*>(Xs) + off);
        }

    #pragma unroll
    for (int ch = 0; ch < 3; ++ch) {
        if (ch) {
            __syncthreads();
            for (int c = t; c < 128 * 16; c += 256) {
                int r = c >> 4, sub = c & 15;
                uint4 v = *reinterpret_cast<const uint4*>(
                    reinterpret_cast<const char*>(Wt) + (size_t)(ch * 128 + r) * 256 + sub * 16);
                int dst = r * 256 + ((sub * 16) ^ ((r & 7) << 4));
                *reinterpret_cast<uint4*>(reinterpret_cast<char*>(Ws) + dst) = v;
            }
            __syncthreads();
        }

        f32x4 acc[2][8];
        const f32x4 zero = {0.f, 0.f, 0.f, 0.f};
        #pragma unroll
        for (int mt = 0; mt < 2; ++mt)
            #pragma unroll
            for (int nt = 0; nt < 8; ++nt) acc[mt][nt] = zero;

        #pragma unroll
        for (int nt = 0; nt < 8; ++nt) {
            bfrag bt[4];
            int row = nt * 16 + lr;
            #pragma unroll
            for (int ks = 0; ks < 4; ++ks) {
                int off = row * 256 + ((ks * 64 + lg * 16) ^ ((row & 7) << 4));
                bt[ks] = *reinterpret_cast<const bfrag*>(
                    reinterpret_cast<const char*>(Ws) + off);
            }
            #pragma unroll
            for (int mt = 0; mt < 2; ++mt)
                #pragma unroll
                for (int ks = 0; ks < 4; ++ks)
                    acc[mt][nt] = __builtin_amdgcn_mfma_f32_16x16x32_bf16(
                        am[mt][ks], bt[ks], acc[mt][nt], 0, 0, 0);
        }

        unsigned short* arr = (ch == 0) ? kk_b : (ch == 1) ? q_b : vv_b;
        #pragma unroll
        for (int nt = 0; nt < 8; ++nt) {
            int ic = nt * 16 + lr;
            float bv = bias[ch * 128 + ic];
            #pragma unroll
            for (int mt = 0; mt < 2; ++mt)
                #pragma unroll
                for (int r = 0; r < 4; ++r) {
                    int row = m0 + wave * 32 + mt * 16 + lg * 4 + r;
                    if (row < M)
                        arr[(size_t)(side_off + row) * 128 + ic] = f2bf(acc[mt][nt][r] + bv);
                }
        }
    }
}

// ---------------------------------------------------------------------------
// CSR build: histogram -> exclusive scan -> fill buckets
// ---------------------------------------------------------------------------
__device__ __forceinline__ void edge_src_dst(
    int e, const int* __restrict__ edge_ui, const int* __restrict__ edge_iu,
    int& src, int& dst)
{
    if (e < E_PER_) {
        src = edge_ui[e];
        dst = edge_ui[E_PER_ + e] + N_USERS;
    } else {
        int e2 = e - E_PER_;
        src = N_USERS + edge_iu[e2];
        dst = edge_iu[E_PER_ + e2];
    }
}

__global__ __launch_bounds__(256) void hist_kernel(
    const int* __restrict__ edge_ui, const int* __restrict__ edge_iu,
    int* __restrict__ cnt)
{
    int e = blockIdx.x * blockDim.x + threadIdx.x;
    if (e >= E_TOT) return;
    int src, dst;
    edge_src_dst(e, edge_ui, edge_iu, src, dst);
    atomicAdd(cnt + dst, 1);
}

__global__ __launch_bounds__(256) void scan1_kernel(
    const int* __restrict__ cnt, int* __restrict__ base, int* __restrict__ bsum)
{
    __shared__ int ssum[256];
    const int t = threadIdx.x;
    const int i0 = blockIdx.x * SCAN_CHUNK + t * 4;
    int v[4];
    #pragma unroll
    for (int j = 0; j < 4; ++j) v[j] = (i0 + j < NN) ? cnt[i0 + j] : 0;
    int tsum = v[0] + v[1] + v[2] + v[3];
    ssum[t] = tsum;
    __syncthreads();
    int run = tsum;
    for (int off = 1; off < 256; off <<= 1) {
        int o = (t >= off) ? ssum[t - off] : 0;
        __syncthreads();
        run += o;
        ssum[t] = run;
        __syncthreads();
    }
    int excl = run - tsum;
    int p = excl;
    #pragma unroll
    for (int j = 0; j < 4; ++j) {
        if (i0 + j < NN) base[i0 + j] = p;
        p += v[j];
    }
    if (t == 255) bsum[blockIdx.x] = run;
}

__global__ void scan2_kernel(int* __restrict__ bsum)
{
    if (threadIdx.x == 0 && blockIdx.x == 0) {
        int run = 0;
        for (int i = 0; i < SCAN_NB; ++i) {
            int v = bsum[i];
            bsum[i] = run;
            run += v;
        }
    }
}

__global__ __launch_bounds__(256) void scan3_kernel(
    int* __restrict__ base, const int* __restrict__ bsum, int* __restrict__ cursor)
{
    int i = blockIdx.x * blockDim.x + threadIdx.x;
    if (i >= NN) return;
    int b = base[i] + bsum[i >> 10];
    base[i] = b;
    cursor[i] = b;
}

__global__ __launch_bounds__(256) void fill_kernel(
    const int* __restrict__ edge_ui, const int* __restrict__ edge_iu,
    int* __restrict__ cursor, int* __restrict__ esrc)
{
    int e = blockIdx.x * blockDim.x + threadIdx.x;
    if (e >= E_TOT) return;
    int src, dst;
    edge_src_dst(e, edge_ui, edge_iu, src, dst);
    int pos = atomicAdd(cursor + dst, 1);
    esrc[pos] = src;
}

// ---------------------------------------------------------------------------
// Fused attention v2: one wave per node, FOUR edges per iteration.
// lane = (g = lane>>4: edge slot, p = lane&15: 16B chunk = dims 8p..8p+7).
// head h = p>>2. Online softmax shared across groups via 2 shfls.
// Output written gelu'd (final GEMM consumes gelu(out) only).
// ---------------------------------------------------------------------------
__global__ __launch_bounds__(256) void attn_fused(
    const unsigned short* __restrict__ q_b, const unsigned short* __restrict__ kk_b,
    const unsigned short* __restrict__ vv_b,
    const int* __restrict__ base, const int* __restrict__ cnt,
    const int* __restrict__ esrc,
    const float* __restrict__ p_ui, const float* __restrict__ p_iu,
    unsigned short* __restrict__ oa)
{
    const int wid  = (blockIdx.x * blockDim.x + threadIdx.x) >> 6;
    const int lane = threadIdx.x & 63;
    const int nw   = (gridDim.x * blockDim.x) >> 6;
    const int g    = lane >> 4;      // edge slot 0..3
    const int p    = lane & 15;      // dims 8p..8p+7
    const int h    = p >> 2;         // head
    const float rsd = 0.17677669529663687f;   // 1/sqrt(32)
    const float pu = p_ui[h], pi = p_iu[h];

    for (int n = wid; n < NN; n += nw) {
        const float pr = (n >= N_USERS) ? pu : pi;
        float qf[8];
        unpack8(*reinterpret_cast<const uint4*>(q_b + (size_t)n * 128 + p * 8), qf);
        float m = -INFINITY, l = 0.f;
        float acc[8] = {0.f, 0.f, 0.f, 0.f, 0.f, 0.f, 0.f, 0.f};
        const int s0 = base[n], c = cnt[n];
        for (int j = 0; j < c; j += 4) {
            int jj = j + g;
            bool valid = jj < c;
            int src = esrc[s0 + (valid ? jj : 0)];
            uint4 k4 = *reinterpret_cast<const uint4*>(kk_b + (size_t)src * 128 + p * 8);
            uint4 v4 = *reinterpret_cast<const uint4*>(vv_b + (size_t)src * 128 + p * 8);
            float kf[8];
            unpack8(k4, kf);
            float s = qf[0] * kf[0];
            #pragma unroll
            for (int i = 1; i < 8; ++i) s = fmaf(qf[i], kf[i], s);
            s += __shfl_xor(s, 1);
            s += __shfl_xor(s, 2);
            float al = valid ? s * pr * rsd : -INFINITY;
            float amx = fmaxf(al, __shfl_xor(al, 16));
            amx = fmaxf(amx, __shfl_xor(amx, 32));
            float nm = fmaxf(m, amx);
            float scale = __expf(m - nm);      // first iter: exp(-inf)=0
            float w = __expf(al - nm);         // invalid slot -> 0
            l = l * scale + w;
            float vf[8];
            unpack8(v4, vf);
            #pragma unroll
            for (int i = 0; i < 8; ++i) acc[i] = fmaf(w, vf[i], acc[i] * scale);
            m = nm;
        }
        // combine the 4 edge-group partials
        l += __shfl_xor(l, 16); l += __shfl_xor(l, 32);
        #pragma unroll
        for (int i = 0; i < 8; ++i) {
            acc[i] += __shfl_xor(acc[i], 16);
            acc[i] += __shfl_xor(acc[i], 32);
        }
        if (g == 0) {
            float inv = 1.0f / (l + 1e-16f);
            uint4 pk;
            unsigned o[4];
            #pragma unroll
            for (int i = 0; i < 4; ++i) {
                float lo = gelu_exact(acc[2 * i] * inv);
                float hi = gelu_exact(acc[2 * i + 1] * inv);
                o[i] = (unsigned)f2bf(lo) | ((unsigned)f2bf(hi) << 16);
            }
            pk.x = o[0]; pk.y = o[1]; pk.z = o[2]; pk.w = o[3];
            *reinterpret_cast<uint4*>(oa + (size_t)n * 128 + p * 8) = pk;
        }
    }
}

// ---------------------------------------------------------------------------
// Final: out = sg*(oa_gelu @ Wo + bo) + (1-sg)*x.  BM=128, bf16 MFMA.
// ---------------------------------------------------------------------------
__global__ __launch_bounds__(256, 2) void final_mfma(
    const unsigned short* __restrict__ oa,   // [M][128] bf16, already gelu'd
    const float* __restrict__ x,
    const unsigned short* __restrict__ Wt,   // [128][128] bf16 (n,k)
    const float* __restrict__ bo,
    const float* __restrict__ skip,
    float* __restrict__ out, int M)
{
    __shared__ unsigned short Ws[128 * 128];  // 32KB
    __shared__ unsigned short Gs[128 * 128];  // 32KB
    const int t = threadIdx.x;
    const int m0 = blockIdx.x * 128;

    for (int c = t; c < 128 * 16; c += 256) {
        int r = c >> 4, sub = c & 15;
        uint4 v = *reinterpret_cast<const uint4*>(
            reinterpret_cast<const char*>(Wt) + r * 256 + sub * 16);
        int dst = r * 256 + ((sub * 16) ^ ((r & 7) << 4));
        *reinterpret_cast<uint4*>(reinterpret_cast<char*>(Ws) + dst) = v;
    }
    for (int c = t; c < 128 * 16; c += 256) {
        int r = c >> 4, sub = c & 15;
        int row = m0 + r;
        uint4 v = make_uint4(0u, 0u, 0u, 0u);
        if (row < M)
            v = *reinterpret_cast<const uint4*>(
                reinterpret_cast<const char*>(oa) + (size_t)row * 256 + sub * 16);
        int dst = r * 256 + ((sub * 16) ^ ((r & 7) << 4));
        *reinterpret_cast<uint4*>(reinterpret_cast<char*>(Gs) + dst) = v;
    }
    __syncthreads();

    const int wave = t >> 6, lane = t & 63;
    const int lr = lane & 15, lg = lane >> 4;

    bfrag am[2][4];
    #pragma unroll
    for (int mt = 0; mt < 2; ++mt)
        #pragma unroll
        for (int ks = 0; ks < 4; ++ks) {
            int row = wave * 32 + mt * 16 + lr;
            int off = row * 256 + ((ks * 64 + lg * 16) ^ ((row & 7) << 4));
            am[mt][ks] = *reinterpret_cast<const bfrag*>(
                reinterpret_cast<const char*>(Gs) + off);
        }

    f32x4 acc[2][8];
    const f32x4 zero = {0.f, 0.f, 0.f, 0.f};
    #pragma unroll
    for (int mt = 0; mt < 2; ++mt)
        #pragma unroll
        for (int nt = 0; nt < 8; ++nt) acc[mt][nt] = zero;

    #pragma unroll
    for (int nt = 0; nt < 8; ++nt) {
        bfrag bt[4];
        int row = nt * 16 + lr;
        #pragma unroll
        for (int ks = 0; ks < 4; ++ks) {
            int off = row * 256 + ((ks * 64 + lg * 16) ^ ((row & 7) << 4));
            bt[ks] = *reinterpret_cast<const bfrag*>(
                reinterpret_cast<const char*>(Ws) + off);
        }
        #pragma unroll
        for (int mt = 0; mt < 2; ++mt)
            #pragma unroll
            for (int ks = 0; ks < 4; ++ks)
                acc[mt][nt] = __builtin_amdgcn_mfma_f32_16x16x32_bf16(
                    am[mt][ks], bt[ks], acc[mt][nt], 0, 0, 0);
    }

    const float sg = 1.0f / (1.0f + expf(-skip[0]));
    #pragma unroll
    for (int nt = 0; nt < 8; ++nt) {
        int col = nt * 16 + lr;
        float bv = bo[col];
        #pragma unroll
        for (int mt = 0; mt < 2; ++mt)
            #pragma unroll
            for (int r = 0; r < 4; ++r) {
                int row = m0 + wave * 32 + mt * 16 + lg * 4 + r;
                if (row < M) {
                    float xv = x[(size_t)row * 128 + col];
                    out[(size_t)row * 128 + col] =
                        sg * (acc[mt][nt][r] + bv) + (1.f - sg) * xv;
                }
            }
    }
}

// ---------------------------------------------------------------------------
extern "C" void kernel_launch(void* const* d_in, const int* in_sizes, int n_in,
                              void* d_out, int out_size, void* d_ws, size_t ws_size,
                              hipStream_t stream)
{
    const float* x_user     = (const float*)d_in[0];
    const float* x_item     = (const float*)d_in[1];
    const float* W_kqv_user = (const float*)d_in[2];
    const float* b_kqv_user = (const float*)d_in[3];
    const float* W_kqv_item = (const float*)d_in[4];
    const float* b_kqv_item = (const float*)d_in[5];
    const float* Wk_rel     = (const float*)d_in[6];
    const float* Wv_rel     = (const float*)d_in[7];
    const float* W_out_user = (const float*)d_in[8];
    const float* b_out_user = (const float*)d_in[9];
    const float* W_out_item = (const float*)d_in[10];
    const float* b_out_item = (const float*)d_in[11];
    const float* skip_user  = (const float*)d_in[12];
    const float* skip_item  = (const float*)d_in[13];
    const float* p_ui       = (const float*)d_in[14];
    const float* p_iu       = (const float*)d_in[15];
    const int*   edge_ui    = (const int*)d_in[16];
    const int*   edge_iu    = (const int*)d_in[17];

    const size_t NODE_F = (size_t)NN * FDIM;     // 12.8M elems
    char* w = (char*)d_ws;
    size_t off = 0;
    auto alloc = [&](size_t bytes) {
        char* p = w + off;
        off += (bytes + 255) & ~(size_t)255;
        return p;
    };
    unsigned short* q_b   = (unsigned short*)alloc(NODE_F * 2);
    unsigned short* kk_b  = (unsigned short*)alloc(NODE_F * 2);
    unsigned short* vv_b  = (unsigned short*)alloc(NODE_F * 2);
    unsigned short* oa_b  = (unsigned short*)alloc(NODE_F * 2);
    int* esrc   = (int*)alloc((size_t)E_TOT * 4);
    int* cnt    = (int*)alloc((size_t)NN * 4);
    int* base   = (int*)alloc((size_t)NN * 4);
    int* cursor = (int*)alloc((size_t)NN * 4);
    int* bsum   = (int*)alloc((size_t)SCAN_NB * 4);
    unsigned short* Wt_u   = (unsigned short*)alloc(384 * 128 * 2);
    unsigned short* Wt_i   = (unsigned short*)alloc(384 * 128 * 2);
    float*          bias_u = (float*)alloc(384 * 4);
    float*          bias_i = (float*)alloc(384 * 4);
    unsigned short* Wo_u   = (unsigned short*)alloc(128 * 128 * 2);
    unsigned short* Wo_i   = (unsigned short*)alloc(128 * 128 * 2);

    // weight prep
    prep_kqv<<<384, 128, 0, stream>>>(W_kqv_user, b_kqv_user, Wk_rel, Wv_rel, 0, Wt_u, bias_u);
    prep_kqv<<<384, 128, 0, stream>>>(W_kqv_item, b_kqv_item, Wk_rel, Wv_rel, 1, Wt_i, bias_i);
    prep_wo<<<64, 256, 0, stream>>>(W_out_user, Wo_u);
    prep_wo<<<64, 256, 0, stream>>>(W_out_item, Wo_i);

    // fused KQV(+rel) GEMM, bf16 MFMA
    const int NB = (N_USERS + 127) / 128;   // 391
    kqv_mfma<<<NB, 256, 0, stream>>>(x_user, Wt_u, bias_u, kk_b, q_b, vv_b, N_USERS, 0);
    kqv_mfma<<<NB, 256, 0, stream>>>(x_item, Wt_i, bias_i, kk_b, q_b, vv_b, N_ITEMS, N_USERS);

    // CSR build
    hipMemsetAsync(cnt, 0, (size_t)NN * 4, stream);
    hist_kernel<<<(E_TOT + 255) / 256, 256, 0, stream>>>(edge_ui, edge_iu, cnt);
    scan1_kernel<<<SCAN_NB, 256, 0, stream>>>(cnt, base, bsum);
    scan2_kernel<<<1, 64, 0, stream>>>(bsum);
    scan3_kernel<<<(NN + 255) / 256, 256, 0, stream>>>(base, bsum, cursor);
    fill_kernel<<<(E_TOT + 255) / 256, 256, 0, stream>>>(edge_ui, edge_iu, cursor, esrc);

    attn_fused<<<2048, 256, 0, stream>>>(q_b, kk_b, vv_b, base, cnt, esrc,
                                         p_ui, p_iu, oa_b);

    final_mfma<<<NB, 256, 0, stream>>>(oa_b, x_user, Wo_u, b_out_user, skip_user,
                                       (float*)d_out, N_USERS);
    final_mfma<<<NB, 256, 0, stream>>>(oa_b + (size_t)N_USERS * FDIM, x_item, Wo_i,
                                       b_out_item, skip_item,
                                       (float*)d_out + (size_t)N_USERS * FDIM, N_ITEMS);
}

// Round 5
// 281.986 us; speedup vs baseline: 4.3763x; 1.0422x over previous
//
#include <hip/hip_runtime.h>
#include <hip/hip_bf16.h>
#include <math.h>

#define N_USERS 50000
#define N_ITEMS 50000
#define NN      100000
#define E_PER_  400000
#define E_TOT   800000
#define FDIM    128
#define NH      4
#define HD      32
#define SCAN_CHUNK 1024
#define SCAN_NB    ((NN + SCAN_CHUNK - 1) / SCAN_CHUNK)   // 98
#define KQV_NB  ((N_USERS + 127) / 128)                   // 391 per side

typedef __attribute__((ext_vector_type(8))) short bfrag;   // 8 bf16 (4 VGPR)
typedef __attribute__((ext_vector_type(4))) float f32x4;

__device__ __forceinline__ float gelu_exact(float x) {
    return 0.5f * x * (1.0f + erff(x * 0.70710678118654752f));
}
__device__ __forceinline__ unsigned short f2bf(float f) {
    unsigned u = __float_as_uint(f);
    unsigned r = u + 0x7fffu + ((u >> 16) & 1u);
    return (unsigned short)(r >> 16);
}
__device__ __forceinline__ void unpack8(uint4 u, float* f) {
    f[0] = __uint_as_float(u.x << 16); f[1] = __uint_as_float(u.x & 0xffff0000u);
    f[2] = __uint_as_float(u.y << 16); f[3] = __uint_as_float(u.y & 0xffff0000u);
    f[4] = __uint_as_float(u.z << 16); f[5] = __uint_as_float(u.z & 0xffff0000u);
    f[6] = __uint_as_float(u.w << 16); f[7] = __uint_as_float(u.w & 0xffff0000u);
}

// ---------------------------------------------------------------------------
// Weight prep (both sides in one launch): fuse rel-transform into KQV weights.
// blockIdx.x in [0,768): n = bid%384, et/side = bid/384.
// ---------------------------------------------------------------------------
__global__ void prep_kqv(
    const float* __restrict__ W_u, const float* __restrict__ b_u,
    const float* __restrict__ W_i, const float* __restrict__ b_i,
    const float* __restrict__ Wk_rel, const float* __restrict__ Wv_rel,
    unsigned short* __restrict__ Wt_u, float* __restrict__ bias_u,
    unsigned short* __restrict__ Wt_i, float* __restrict__ bias_i)
{
    const int et = blockIdx.x >> 9 ? 1 : (blockIdx.x >= 384);   // 0 or 1
    const int n = blockIdx.x - et * 384;   // 0..383
    const int k = threadIdx.x;             // 0..127
    const float* W = et ? W_i : W_u;
    const float* b = et ? b_i : b_u;
    unsigned short* Wt = et ? Wt_i : Wt_u;
    float* bias_f = et ? bias_i : bias_u;
    float s;
    if (n < 128) {
        int h = n >> 5, e = n & 31;
        const float* wr = Wk_rel + (size_t)(h * 2 + et) * 1024 + e;
        const float* wc = W + (size_t)k * 384 + h * 32;
        s = 0.f;
        for (int d = 0; d < 32; ++d) s = fmaf(wc[d], wr[d * 32], s);
        if (k == 0) {
            float bs = 0.f;
            for (int d = 0; d < 32; ++d) bs = fmaf(b[h * 32 + d], wr[d * 32], bs);
            bias_f[n] = bs;
        }
    } else if (n < 256) {
        s = W[(size_t)k * 384 + n];
        if (k == 0) bias_f[n] = b[n];
    } else {
        int h = (n - 256) >> 5, e = (n - 256) & 31;
        const float* wr = Wv_rel + (size_t)(h * 2 + et) * 1024 + e;
        const float* wc = W + (size_t)k * 384 + 256 + h * 32;
        s = 0.f;
        for (int d = 0; d < 32; ++d) s = fmaf(wc[d], wr[d * 32], s);
        if (k == 0) {
            float bs = 0.f;
            for (int d = 0; d < 32; ++d) bs = fmaf(b[256 + h * 32 + d], wr[d * 32], bs);
            bias_f[n] = bs;
        }
    }
    Wt[(size_t)n * 128 + k] = f2bf(s);
}

__global__ void prep_wo(
    const float* __restrict__ W_u, unsigned short* __restrict__ Wt_u,
    const float* __restrict__ W_i, unsigned short* __restrict__ Wt_i)
{
    int i = blockIdx.x * blockDim.x + threadIdx.x;
    int side = i >= 128 * 128;
    int j = i - side * 128 * 128;
    if (j >= 128 * 128) return;
    int nrow = j >> 7, k = j & 127;
    const float* W = side ? W_i : W_u;
    unsigned short* Wt = side ? Wt_i : Wt_u;
    Wt[j] = f2bf(W[(size_t)k * 128 + nrow]);
}

// ---------------------------------------------------------------------------
// KQV GEMM, both sides in one launch. BM=128, three 128-col W chunks.
// LDS 64KB (Xs 32 + Ws 32), XOR-swizzled both sides.
// ---------------------------------------------------------------------------
__global__ __launch_bounds__(256, 2) void kqv_mfma(
    const float* __restrict__ X_u, const unsigned short* __restrict__ Wt_u,
    const float* __restrict__ bias_u,
    const float* __restrict__ X_i, const unsigned short* __restrict__ Wt_i,
    const float* __restrict__ bias_i,
    unsigned short* __restrict__ kk_b,
    unsigned short* __restrict__ q_b,
    unsigned short* __restrict__ vv_b)
{
    __shared__ unsigned short Xs[128 * 128];  // 32KB
    __shared__ unsigned short Ws[128 * 128];  // 32KB
    const int t = threadIdx.x;
    const int side = blockIdx.x >= KQV_NB;
    const int m0 = (blockIdx.x - side * KQV_NB) * 128;
    const float* X = side ? X_i : X_u;
    const unsigned short* Wt = side ? Wt_i : Wt_u;
    const float* bias = side ? bias_i : bias_u;
    const int side_off = side ? N_USERS : 0;
    const int M = N_USERS;   // both sides 50000

    for (int c = t; c < 128 * 16; c += 256) {
        int r = c >> 4, sub = c & 15;
        int row = m0 + r;
        float4 a = make_float4(0.f, 0.f, 0.f, 0.f);
        float4 b4 = make_float4(0.f, 0.f, 0.f, 0.f);
        if (row < M) {
            a  = *reinterpret_cast<const float4*>(X + (size_t)row * 128 + sub * 8);
            b4 = *reinterpret_cast<const float4*>(X + (size_t)row * 128 + sub * 8 + 4);
        }
        uint4 pk;
        pk.x = (unsigned)f2bf(a.x)  | ((unsigned)f2bf(a.y)  << 16);
        pk.y = (unsigned)f2bf(a.z)  | ((unsigned)f2bf(a.w)  << 16);
        pk.z = (unsigned)f2bf(b4.x) | ((unsigned)f2bf(b4.y) << 16);
        pk.w = (unsigned)f2bf(b4.z) | ((unsigned)f2bf(b4.w) << 16);
        int dst = r * 256 + ((sub * 16) ^ ((r & 7) << 4));
        *reinterpret_cast<uint4*>(reinterpret_cast<char*>(Xs) + dst) = pk;
    }
    for (int c = t; c < 128 * 16; c += 256) {
        int r = c >> 4, sub = c & 15;
        uint4 v = *reinterpret_cast<const uint4*>(
            reinterpret_cast<const char*>(Wt) + (size_t)r * 256 + sub * 16);
        int dst = r * 256 + ((sub * 16) ^ ((r & 7) << 4));
        *reinterpret_cast<uint4*>(reinterpret_cast<char*>(Ws) + dst) = v;
    }
    __syncthreads();

    const int wave = t >> 6, lane = t & 63;
    const int lr = lane & 15, lg = lane >> 4;

    bfrag am[2][4];
    #pragma unroll
    for (int mt = 0; mt < 2; ++mt)
        #pragma unroll
        for (int ks = 0; ks < 4; ++ks) {
            int row = wave * 32 + mt * 16 + lr;
            int off = row * 256 + ((ks * 64 + lg * 16) ^ ((row & 7) << 4));
            am[mt][ks] = *reinterpret_cast<const bfrag*>(
                reinterpret_cast<const char*>(Xs) + off);
        }

    #pragma unroll
    for (int ch = 0; ch < 3; ++ch) {
        if (ch) {
            __syncthreads();
            for (int c = t; c < 128 * 16; c += 256) {
                int r = c >> 4, sub = c & 15;
                uint4 v = *reinterpret_cast<const uint4*>(
                    reinterpret_cast<const char*>(Wt) + (size_t)(ch * 128 + r) * 256 + sub * 16);
                int dst = r * 256 + ((sub * 16) ^ ((r & 7) << 4));
                *reinterpret_cast<uint4*>(reinterpret_cast<char*>(Ws) + dst) = v;
            }
            __syncthreads();
        }

        f32x4 acc[2][8];
        const f32x4 zero = {0.f, 0.f, 0.f, 0.f};
        #pragma unroll
        for (int mt = 0; mt < 2; ++mt)
            #pragma unroll
            for (int nt = 0; nt < 8; ++nt) acc[mt][nt] = zero;

        #pragma unroll
        for (int nt = 0; nt < 8; ++nt) {
            bfrag bt[4];
            int row = nt * 16 + lr;
            #pragma unroll
            for (int ks = 0; ks < 4; ++ks) {
                int off = row * 256 + ((ks * 64 + lg * 16) ^ ((row & 7) << 4));
                bt[ks] = *reinterpret_cast<const bfrag*>(
                    reinterpret_cast<const char*>(Ws) + off);
            }
            #pragma unroll
            for (int mt = 0; mt < 2; ++mt)
                #pragma unroll
                for (int ks = 0; ks < 4; ++ks)
                    acc[mt][nt] = __builtin_amdgcn_mfma_f32_16x16x32_bf16(
                        am[mt][ks], bt[ks], acc[mt][nt], 0, 0, 0);
        }

        unsigned short* arr = (ch == 0) ? kk_b : (ch == 1) ? q_b : vv_b;
        #pragma unroll
        for (int nt = 0; nt < 8; ++nt) {
            int ic = nt * 16 + lr;
            float bv = bias[ch * 128 + ic];
            #pragma unroll
            for (int mt = 0; mt < 2; ++mt)
                #pragma unroll
                for (int r = 0; r < 4; ++r) {
                    int row = m0 + wave * 32 + mt * 16 + lg * 4 + r;
                    if (row < M)
                        arr[(size_t)(side_off + row) * 128 + ic] = f2bf(acc[mt][nt][r] + bv);
                }
        }
    }
}

// ---------------------------------------------------------------------------
// CSR build: histogram -> exclusive scan -> fill buckets
// ---------------------------------------------------------------------------
__device__ __forceinline__ void edge_src_dst(
    int e, const int* __restrict__ edge_ui, const int* __restrict__ edge_iu,
    int& src, int& dst)
{
    if (e < E_PER_) {
        src = edge_ui[e];
        dst = edge_ui[E_PER_ + e] + N_USERS;
    } else {
        int e2 = e - E_PER_;
        src = N_USERS + edge_iu[e2];
        dst = edge_iu[E_PER_ + e2];
    }
}

__global__ __launch_bounds__(256) void hist_kernel(
    const int* __restrict__ edge_ui, const int* __restrict__ edge_iu,
    int* __restrict__ cnt)
{
    int e = blockIdx.x * blockDim.x + threadIdx.x;
    if (e >= E_TOT) return;
    int src, dst;
    edge_src_dst(e, edge_ui, edge_iu, src, dst);
    atomicAdd(cnt + dst, 1);
}

__global__ __launch_bounds__(256) void scan1_kernel(
    const int* __restrict__ cnt, int* __restrict__ base, int* __restrict__ bsum)
{
    __shared__ int ssum[256];
    const int t = threadIdx.x;
    const int i0 = blockIdx.x * SCAN_CHUNK + t * 4;
    int v[4];
    #pragma unroll
    for (int j = 0; j < 4; ++j) v[j] = (i0 + j < NN) ? cnt[i0 + j] : 0;
    int tsum = v[0] + v[1] + v[2] + v[3];
    ssum[t] = tsum;
    __syncthreads();
    int run = tsum;
    for (int off = 1; off < 256; off <<= 1) {
        int o = (t >= off) ? ssum[t - off] : 0;
        __syncthreads();
        run += o;
        ssum[t] = run;
        __syncthreads();
    }
    int excl = run - tsum;
    int p = excl;
    #pragma unroll
    for (int j = 0; j < 4; ++j) {
        if (i0 + j < NN) base[i0 + j] = p;
        p += v[j];
    }
    if (t == 255) bsum[blockIdx.x] = run;
}

// wave-parallel exclusive scan of SCAN_NB (<=128) block sums, 64 threads
__global__ void scan2_kernel(int* __restrict__ bsum)
{
    const int lane = threadIdx.x;   // 0..63
    int a = (lane < SCAN_NB) ? bsum[lane] : 0;
    int b = (64 + lane < SCAN_NB) ? bsum[64 + lane] : 0;
    int sa = a, sb = b;
    for (int off = 1; off < 64; off <<= 1) {
        int ta = __shfl_up(sa, off);
        int tb = __shfl_up(sb, off);
        if (lane >= off) { sa += ta; sb += tb; }
    }
    int total0 = __shfl(sa, 63);
    if (lane < SCAN_NB) bsum[lane] = sa - a;
    if (64 + lane < SCAN_NB) bsum[64 + lane] = total0 + sb - b;
}

__global__ __launch_bounds__(256) void scan3_kernel(
    int* __restrict__ base, const int* __restrict__ bsum, int* __restrict__ cursor)
{
    int i = blockIdx.x * blockDim.x + threadIdx.x;
    if (i >= NN) return;
    int b = base[i] + bsum[i >> 10];
    base[i] = b;
    cursor[i] = b;
}

__global__ __launch_bounds__(256) void fill_kernel(
    const int* __restrict__ edge_ui, const int* __restrict__ edge_iu,
    int* __restrict__ cursor, int* __restrict__ esrc)
{
    int e = blockIdx.x * blockDim.x + threadIdx.x;
    if (e >= E_TOT) return;
    int src, dst;
    edge_src_dst(e, edge_ui, edge_iu, src, dst);
    int pos = atomicAdd(cursor + dst, 1);
    esrc[pos] = src;
}

// ---------------------------------------------------------------------------
// Fused attention v3: wave/node, 4 edges/iter, software-pipelined gathers,
// defer-rescale (THR=8). Output written gelu'd bf16.
// ---------------------------------------------------------------------------
__global__ __launch_bounds__(256) void attn_fused(
    const unsigned short* __restrict__ q_b, const unsigned short* __restrict__ kk_b,
    const unsigned short* __restrict__ vv_b,
    const int* __restrict__ base, const int* __restrict__ cnt,
    const int* __restrict__ esrc,
    const float* __restrict__ p_ui, const float* __restrict__ p_iu,
    unsigned short* __restrict__ oa)
{
    const int wid  = (blockIdx.x * blockDim.x + threadIdx.x) >> 6;
    const int lane = threadIdx.x & 63;
    const int nw   = (gridDim.x * blockDim.x) >> 6;
    const int g    = lane >> 4;      // edge slot 0..3
    const int p    = lane & 15;      // dims 8p..8p+7
    const int h    = p >> 2;         // head
    const float rsd = 0.17677669529663687f;   // 1/sqrt(32)
    const float pu = p_ui[h], pi = p_iu[h];

    for (int n = wid; n < NN; n += nw) {
        const float pr = (n >= N_USERS) ? pu : pi;
        float qf[8];
        unpack8(*reinterpret_cast<const uint4*>(q_b + (size_t)n * 128 + p * 8), qf);
        float m = -INFINITY, l = 0.f;
        float acc[8] = {0.f, 0.f, 0.f, 0.f, 0.f, 0.f, 0.f, 0.f};
        const int s0 = base[n], c = cnt[n];

        if (c > 0) {
            bool valid = g < c;
            int src = esrc[s0 + (valid ? g : 0)];
            uint4 k4 = *reinterpret_cast<const uint4*>(kk_b + (size_t)src * 128 + p * 8);
            uint4 v4 = *reinterpret_cast<const uint4*>(vv_b + (size_t)src * 128 + p * 8);

            for (int j = 0; j < c; j += 4) {
                // prefetch next iteration's gathers (wave-uniform guard)
                uint4 k4n, v4n;
                bool validn = false;
                if (j + 4 < c) {
                    int jn = j + 4 + g;
                    validn = jn < c;
                    int srcn = esrc[s0 + (validn ? jn : 0)];
                    k4n = *reinterpret_cast<const uint4*>(kk_b + (size_t)srcn * 128 + p * 8);
                    v4n = *reinterpret_cast<const uint4*>(vv_b + (size_t)srcn * 128 + p * 8);
                }

                float kf[8];
                unpack8(k4, kf);
                float s = qf[0] * kf[0];
                #pragma unroll
                for (int i = 1; i < 8; ++i) s = fmaf(qf[i], kf[i], s);
                s += __shfl_xor(s, 1);
                s += __shfl_xor(s, 2);
                float al = valid ? s * pr * rsd : -INFINITY;
                float amx = fmaxf(al, __shfl_xor(al, 16));
                amx = fmaxf(amx, __shfl_xor(amx, 32));
                if (__any(amx > m + 8.f)) {          // defer-rescale
                    float nm = fmaxf(m, amx);
                    float scale = __expf(m - nm);    // first iter: exp(-inf)=0
                    l *= scale;
                    #pragma unroll
                    for (int i = 0; i < 8; ++i) acc[i] *= scale;
                    m = nm;
                }
                float w = __expf(al - m);            // bounded by e^8; invalid -> 0
                l += w;
                float vf[8];
                unpack8(v4, vf);
                #pragma unroll
                for (int i = 0; i < 8; ++i) acc[i] = fmaf(w, vf[i], acc[i]);

                k4 = k4n; v4 = v4n; valid = validn;
            }
        }

        // combine the 4 edge-group partials
        l += __shfl_xor(l, 16); l += __shfl_xor(l, 32);
        #pragma unroll
        for (int i = 0; i < 8; ++i) {
            acc[i] += __shfl_xor(acc[i], 16);
            acc[i] += __shfl_xor(acc[i], 32);
        }
        if (g == 0) {
            float inv = 1.0f / (l + 1e-16f);
            uint4 pk;
            unsigned o[4];
            #pragma unroll
            for (int i = 0; i < 4; ++i) {
                float lo = gelu_exact(acc[2 * i] * inv);
                float hi = gelu_exact(acc[2 * i + 1] * inv);
                o[i] = (unsigned)f2bf(lo) | ((unsigned)f2bf(hi) << 16);
            }
            pk.x = o[0]; pk.y = o[1]; pk.z = o[2]; pk.w = o[3];
            *reinterpret_cast<uint4*>(oa + (size_t)n * 128 + p * 8) = pk;
        }
    }
}

// ---------------------------------------------------------------------------
// Final (both sides, one launch): out = sg*(oa_gelu @ Wo + bo) + (1-sg)*x.
// ---------------------------------------------------------------------------
__global__ __launch_bounds__(256, 2) void final_mfma(
    const unsigned short* __restrict__ oa,   // [NN][128] bf16, gelu'd
    const float* __restrict__ x_u, const unsigned short* __restrict__ Wt_u,
    const float* __restrict__ bo_u, const float* __restrict__ skip_u,
    const float* __restrict__ x_i, const unsigned short* __restrict__ Wt_i,
    const float* __restrict__ bo_i, const float* __restrict__ skip_i,
    float* __restrict__ out)
{
    __shared__ unsigned short Ws[128 * 128];  // 32KB
    __shared__ unsigned short Gs[128 * 128];  // 32KB
    const int t = threadIdx.x;
    const int side = blockIdx.x >= KQV_NB;
    const int m0 = (blockIdx.x - side * KQV_NB) * 128;
    const float* x = side ? x_i : x_u;
    const unsigned short* Wt = side ? Wt_i : Wt_u;
    const float* bo = side ? bo_i : bo_u;
    const float* skip = side ? skip_i : skip_u;
    const int row_off = side ? N_USERS : 0;
    const int M = N_USERS;

    for (int c = t; c < 128 * 16; c += 256) {
        int r = c >> 4, sub = c & 15;
        uint4 v = *reinterpret_cast<const uint4*>(
            reinterpret_cast<const char*>(Wt) + r * 256 + sub * 16);
        int dst = r * 256 + ((sub * 16) ^ ((r & 7) << 4));
        *reinterpret_cast<uint4*>(reinterpret_cast<char*>(Ws) + dst) = v;
    }
    for (int c = t; c < 128 * 16; c += 256) {
        int r = c >> 4, sub = c & 15;
        int row = m0 + r;
        uint4 v = make_uint4(0u, 0u, 0u, 0u);
        if (row < M)
            v = *reinterpret_cast<const uint4*>(
                reinterpret_cast<const char*>(oa) + (size_t)(row_off + row) * 256 + sub * 16);
        int dst = r * 256 + ((sub * 16) ^ ((r & 7) << 4));
        *reinterpret_cast<uint4*>(reinterpret_cast<char*>(Gs) + dst) = v;
    }
    __syncthreads();

    const int wave = t >> 6, lane = t & 63;
    const int lr = lane & 15, lg = lane >> 4;

    bfrag am[2][4];
    #pragma unroll
    for (int mt = 0; mt < 2; ++mt)
        #pragma unroll
        for (int ks = 0; ks < 4; ++ks) {
            int row = wave * 32 + mt * 16 + lr;
            int off = row * 256 + ((ks * 64 + lg * 16) ^ ((row & 7) << 4));
            am[mt][ks] = *reinterpret_cast<const bfrag*>(
                reinterpret_cast<const char*>(Gs) + off);
        }

    f32x4 acc[2][8];
    const f32x4 zero = {0.f, 0.f, 0.f, 0.f};
    #pragma unroll
    for (int mt = 0; mt < 2; ++mt)
        #pragma unroll
        for (int nt = 0; nt < 8; ++nt) acc[mt][nt] = zero;

    #pragma unroll
    for (int nt = 0; nt < 8; ++nt) {
        bfrag bt[4];
        int row = nt * 16 + lr;
        #pragma unroll
        for (int ks = 0; ks < 4; ++ks) {
            int off = row * 256 + ((ks * 64 + lg * 16) ^ ((row & 7) << 4));
            bt[ks] = *reinterpret_cast<const bfrag*>(
                reinterpret_cast<const char*>(Ws) + off);
        }
        #pragma unroll
        for (int mt = 0; mt < 2; ++mt)
            #pragma unroll
            for (int ks = 0; ks < 4; ++ks)
                acc[mt][nt] = __builtin_amdgcn_mfma_f32_16x16x32_bf16(
                    am[mt][ks], bt[ks], acc[mt][nt], 0, 0, 0);
    }

    const float sg = 1.0f / (1.0f + expf(-skip[0]));
    #pragma unroll
    for (int nt = 0; nt < 8; ++nt) {
        int col = nt * 16 + lr;
        float bv = bo[col];
        #pragma unroll
        for (int mt = 0; mt < 2; ++mt)
            #pragma unroll
            for (int r = 0; r < 4; ++r) {
                int row = m0 + wave * 32 + mt * 16 + lg * 4 + r;
                if (row < M) {
                    float xv = x[(size_t)row * 128 + col];
                    out[(size_t)(row_off + row) * 128 + col] =
                        sg * (acc[mt][nt][r] + bv) + (1.f - sg) * xv;
                }
            }
    }
}

// ---------------------------------------------------------------------------
extern "C" void kernel_launch(void* const* d_in, const int* in_sizes, int n_in,
                              void* d_out, int out_size, void* d_ws, size_t ws_size,
                              hipStream_t stream)
{
    const float* x_user     = (const float*)d_in[0];
    const float* x_item     = (const float*)d_in[1];
    const float* W_kqv_user = (const float*)d_in[2];
    const float* b_kqv_user = (const float*)d_in[3];
    const float* W_kqv_item = (const float*)d_in[4];
    const float* b_kqv_item = (const float*)d_in[5];
    const float* Wk_rel     = (const float*)d_in[6];
    const float* Wv_rel     = (const float*)d_in[7];
    const float* W_out_user = (const float*)d_in[8];
    const float* b_out_user = (const float*)d_in[9];
    const float* W_out_item = (const float*)d_in[10];
    const float* b_out_item = (const float*)d_in[11];
    const float* skip_user  = (const float*)d_in[12];
    const float* skip_item  = (const float*)d_in[13];
    const float* p_ui       = (const float*)d_in[14];
    const float* p_iu       = (const float*)d_in[15];
    const int*   edge_ui    = (const int*)d_in[16];
    const int*   edge_iu    = (const int*)d_in[17];

    const size_t NODE_F = (size_t)NN * FDIM;     // 12.8M elems
    char* w = (char*)d_ws;
    size_t off = 0;
    auto alloc = [&](size_t bytes) {
        char* p = w + off;
        off += (bytes + 255) & ~(size_t)255;
        return p;
    };
    unsigned short* q_b   = (unsigned short*)alloc(NODE_F * 2);
    unsigned short* kk_b  = (unsigned short*)alloc(NODE_F * 2);
    unsigned short* vv_b  = (unsigned short*)alloc(NODE_F * 2);
    unsigned short* oa_b  = (unsigned short*)alloc(NODE_F * 2);
    int* esrc   = (int*)alloc((size_t)E_TOT * 4);
    int* cnt    = (int*)alloc((size_t)NN * 4);
    int* base   = (int*)alloc((size_t)NN * 4);
    int* cursor = (int*)alloc((size_t)NN * 4);
    int* bsum   = (int*)alloc((size_t)SCAN_NB * 4);
    unsigned short* Wt_u   = (unsigned short*)alloc(384 * 128 * 2);
    unsigned short* Wt_i   = (unsigned short*)alloc(384 * 128 * 2);
    float*          bias_u = (float*)alloc(384 * 4);
    float*          bias_i = (float*)alloc(384 * 4);
    unsigned short* Wo_u   = (unsigned short*)alloc(128 * 128 * 2);
    unsigned short* Wo_i   = (unsigned short*)alloc(128 * 128 * 2);

    // weight prep (fused launches)
    prep_kqv<<<768, 128, 0, stream>>>(W_kqv_user, b_kqv_user, W_kqv_item, b_kqv_item,
                                      Wk_rel, Wv_rel, Wt_u, bias_u, Wt_i, bias_i);
    prep_wo<<<128, 256, 0, stream>>>(W_out_user, Wo_u, W_out_item, Wo_i);

    // fused KQV(+rel) GEMM, both sides
    kqv_mfma<<<2 * KQV_NB, 256, 0, stream>>>(x_user, Wt_u, bias_u,
                                             x_item, Wt_i, bias_i,
                                             kk_b, q_b, vv_b);

    // CSR build
    hipMemsetAsync(cnt, 0, (size_t)NN * 4, stream);
    hist_kernel<<<(E_TOT + 255) / 256, 256, 0, stream>>>(edge_ui, edge_iu, cnt);
    scan1_kernel<<<SCAN_NB, 256, 0, stream>>>(cnt, base, bsum);
    scan2_kernel<<<1, 64, 0, stream>>>(bsum);
    scan3_kernel<<<(NN + 255) / 256, 256, 0, stream>>>(base, bsum, cursor);
    fill_kernel<<<(E_TOT + 255) / 256, 256, 0, stream>>>(edge_ui, edge_iu, cursor, esrc);

    attn_fused<<<2048, 256, 0, stream>>>(q_b, kk_b, vv_b, base, cnt, esrc,
                                         p_ui, p_iu, oa_b);

    // final GEMM, both sides
    final_mfma<<<2 * KQV_NB, 256, 0, stream>>>(
        oa_b, x_user, Wo_u, b_out_user, skip_user,
        x_item, Wo_i, b_out_item, skip_item, (float*)d_out);
}

// Round 6
// 241.977 us; speedup vs baseline: 5.0999x; 1.1653x over previous
//
#include <hip/hip_runtime.h>
#include <hip/hip_bf16.h>
#include <math.h>

#define N_USERS 50000
#define N_ITEMS 50000
#define NN      100000
#define E_PER_  400000
#define E_TOT   800000
#define FDIM    128
#define NH      4
#define HD      32
#define SCAN_CHUNK 1024
#define SCAN_NB    ((NN + SCAN_CHUNK - 1) / SCAN_CHUNK)   // 98
#define KQV_NB  ((N_USERS + 127) / 128)                   // 391 per side

typedef __attribute__((ext_vector_type(8))) short bfrag;   // 8 bf16 (4 VGPR)
typedef __attribute__((ext_vector_type(4))) float f32x4;

__device__ __forceinline__ float gelu_exact(float x) {
    return 0.5f * x * (1.0f + erff(x * 0.70710678118654752f));
}
__device__ __forceinline__ unsigned short f2bf(float f) {
    unsigned u = __float_as_uint(f);
    unsigned r = u + 0x7fffu + ((u >> 16) & 1u);
    return (unsigned short)(r >> 16);
}
__device__ __forceinline__ void unpack8(uint4 u, float* f) {
    f[0] = __uint_as_float(u.x << 16); f[1] = __uint_as_float(u.x & 0xffff0000u);
    f[2] = __uint_as_float(u.y << 16); f[3] = __uint_as_float(u.y & 0xffff0000u);
    f[4] = __uint_as_float(u.z << 16); f[5] = __uint_as_float(u.z & 0xffff0000u);
    f[6] = __uint_as_float(u.w << 16); f[7] = __uint_as_float(u.w & 0xffff0000u);
}
// fragment slot index for A-operand W (16B per lane): n = matrix row, k = contraction
__device__ __forceinline__ size_t wfrag_idx(int n, int k) {
    int ch = n >> 7, nt = (n >> 4) & 7, lr = n & 15;
    int ks = k >> 5, lg = (k >> 3) & 3, e = k & 7;
    return ((size_t)(((ch * 8 + nt) * 4 + ks) * 64 + lg * 16 + lr)) * 8 + e;
}

// ---------------------------------------------------------------------------
// Weight prep: fuse rel-transform into KQV weights; emit in MFMA frag layout.
// blockIdx.x in [0,768): n = bid%384, et/side = bid/384. thread k = 0..127.
// ---------------------------------------------------------------------------
__global__ void prep_kqv(
    const float* __restrict__ W_u, const float* __restrict__ b_u,
    const float* __restrict__ W_i, const float* __restrict__ b_i,
    const float* __restrict__ Wk_rel, const float* __restrict__ Wv_rel,
    unsigned short* __restrict__ F_u, float* __restrict__ bias_u,
    unsigned short* __restrict__ F_i, float* __restrict__ bias_i)
{
    const int et = blockIdx.x >= 384;
    const int n = blockIdx.x - et * 384;   // 0..383
    const int k = threadIdx.x;             // 0..127
    const float* W = et ? W_i : W_u;
    const float* b = et ? b_i : b_u;
    unsigned short* F = et ? F_i : F_u;
    float* bias_f = et ? bias_i : bias_u;
    float s;
    if (n < 128) {
        int h = n >> 5, e = n & 31;
        const float* wr = Wk_rel + (size_t)(h * 2 + et) * 1024 + e;
        const float* wc = W + (size_t)k * 384 + h * 32;
        s = 0.f;
        for (int d = 0; d < 32; ++d) s = fmaf(wc[d], wr[d * 32], s);
        if (k == 0) {
            float bs = 0.f;
            for (int d = 0; d < 32; ++d) bs = fmaf(b[h * 32 + d], wr[d * 32], bs);
            bias_f[n] = bs;
        }
    } else if (n < 256) {
        s = W[(size_t)k * 384 + n];
        if (k == 0) bias_f[n] = b[n];
    } else {
        int h = (n - 256) >> 5, e = (n - 256) & 31;
        const float* wr = Wv_rel + (size_t)(h * 2 + et) * 1024 + e;
        const float* wc = W + (size_t)k * 384 + 256 + h * 32;
        s = 0.f;
        for (int d = 0; d < 32; ++d) s = fmaf(wc[d], wr[d * 32], s);
        if (k == 0) {
            float bs = 0.f;
            for (int d = 0; d < 32; ++d) bs = fmaf(b[256 + h * 32 + d], wr[d * 32], bs);
            bias_f[n] = bs;
        }
    }
    F[wfrag_idx(n, k)] = f2bf(s);
}

// W_out[k][n] f32 -> frag layout bf16 (single 128-chunk)
__global__ void prep_wo(
    const float* __restrict__ W_u, unsigned short* __restrict__ F_u,
    const float* __restrict__ W_i, unsigned short* __restrict__ F_i)
{
    int i = blockIdx.x * blockDim.x + threadIdx.x;   // 0..2*16384
    int side = i >= 128 * 128;
    int j = i - side * 128 * 128;
    if (j >= 128 * 128) return;
    int n = j >> 7, k = j & 127;
    const float* W = side ? W_i : W_u;
    unsigned short* F = side ? F_i : F_u;
    F[wfrag_idx(n, k)] = f2bf(W[(size_t)k * 128 + n]);
}

// ---------------------------------------------------------------------------
// KQV GEMM, LDS-free. BM=128 (4 waves x 32 rows), N=384 in 3 chunks.
// X-frags from global f32 (packed to bf16 in regs); W-frags coalesced from
// frag-layout buffer (L2-resident); swapped mfma -> 8B contiguous stores.
// ---------------------------------------------------------------------------
__global__ __launch_bounds__(256, 3) void kqv_mfma(
    const float* __restrict__ X_u, const unsigned short* __restrict__ F_u,
    const float* __restrict__ bias_u,
    const float* __restrict__ X_i, const unsigned short* __restrict__ F_i,
    const float* __restrict__ bias_i,
    unsigned short* __restrict__ kk_b,
    unsigned short* __restrict__ q_b,
    unsigned short* __restrict__ vv_b)
{
    const int t = threadIdx.x;
    const int side = blockIdx.x >= KQV_NB;
    const int m0 = (blockIdx.x - side * KQV_NB) * 128;
    const float* X = side ? X_i : X_u;
    const unsigned short* F = side ? F_i : F_u;
    const float* bias = side ? bias_i : bias_u;
    const int side_off = side ? N_USERS : 0;
    const int M = N_USERS;

    const int wave = t >> 6, lane = t & 63;
    const int lr = lane & 15, lg = lane >> 4;
    const int rbase = m0 + wave * 32;

    // X fragments (B operand): row=rbase+mt*16+lr, k=ks*32+lg*8 .. +8
    bfrag am[2][4];
    #pragma unroll
    for (int mt = 0; mt < 2; ++mt)
        #pragma unroll
        for (int ks = 0; ks < 4; ++ks) {
            int row = rbase + mt * 16 + lr;
            float4 a = make_float4(0.f, 0.f, 0.f, 0.f);
            float4 b4 = make_float4(0.f, 0.f, 0.f, 0.f);
            if (row < M) {
                const float* px = X + (size_t)row * 128 + ks * 32 + lg * 8;
                a  = *reinterpret_cast<const float4*>(px);
                b4 = *reinterpret_cast<const float4*>(px + 4);
            }
            uint4 pk;
            pk.x = (unsigned)f2bf(a.x)  | ((unsigned)f2bf(a.y)  << 16);
            pk.y = (unsigned)f2bf(a.z)  | ((unsigned)f2bf(a.w)  << 16);
            pk.z = (unsigned)f2bf(b4.x) | ((unsigned)f2bf(b4.y) << 16);
            pk.w = (unsigned)f2bf(b4.z) | ((unsigned)f2bf(b4.w) << 16);
            am[mt][ks] = *reinterpret_cast<bfrag*>(&pk);
        }

    #pragma unroll
    for (int ch = 0; ch < 3; ++ch) {
        f32x4 acc[2][8];
        const f32x4 zero = {0.f, 0.f, 0.f, 0.f};
        #pragma unroll
        for (int mt = 0; mt < 2; ++mt)
            #pragma unroll
            for (int nt = 0; nt < 8; ++nt) acc[mt][nt] = zero;

        bfrag bc[4], bn[4];
        #pragma unroll
        for (int ks = 0; ks < 4; ++ks)
            bc[ks] = *reinterpret_cast<const bfrag*>(
                F + ((size_t)((ch * 8 + 0) * 4 + ks) * 64 + lane) * 8);

        #pragma unroll
        for (int nt = 0; nt < 8; ++nt) {
            if (nt < 7) {
                #pragma unroll
                for (int ks = 0; ks < 4; ++ks)
                    bn[ks] = *reinterpret_cast<const bfrag*>(
                        F + ((size_t)((ch * 8 + nt + 1) * 4 + ks) * 64 + lane) * 8);
            }
            #pragma unroll
            for (int mt = 0; mt < 2; ++mt)
                #pragma unroll
                for (int ks = 0; ks < 4; ++ks)
                    acc[mt][nt] = __builtin_amdgcn_mfma_f32_16x16x32_bf16(
                        bc[ks], am[mt][ks], acc[mt][nt], 0, 0, 0);
            #pragma unroll
            for (int ks = 0; ks < 4; ++ks) bc[ks] = bn[ks];
        }

        // epilogue: D col(lane&15)=X row, D rows(lg*4+r)=4 consecutive n
        unsigned short* arr = (ch == 0) ? kk_b : (ch == 1) ? q_b : vv_b;
        #pragma unroll
        for (int nt = 0; nt < 8; ++nt) {
            float4 bv = *reinterpret_cast<const float4*>(bias + ch * 128 + nt * 16 + lg * 4);
            #pragma unroll
            for (int mt = 0; mt < 2; ++mt) {
                int row = rbase + mt * 16 + lr;
                if (row < M) {
                    unsigned lo = (unsigned)f2bf(acc[mt][nt][0] + bv.x)
                                | ((unsigned)f2bf(acc[mt][nt][1] + bv.y) << 16);
                    unsigned hi = (unsigned)f2bf(acc[mt][nt][2] + bv.z)
                                | ((unsigned)f2bf(acc[mt][nt][3] + bv.w) << 16);
                    uint2 st = make_uint2(lo, hi);
                    *reinterpret_cast<uint2*>(
                        arr + (size_t)(side_off + row) * 128 + nt * 16 + lg * 4) = st;
                }
            }
        }
    }
}

// ---------------------------------------------------------------------------
// CSR build: histogram -> exclusive scan -> fill buckets
// ---------------------------------------------------------------------------
__device__ __forceinline__ void edge_src_dst(
    int e, const int* __restrict__ edge_ui, const int* __restrict__ edge_iu,
    int& src, int& dst)
{
    if (e < E_PER_) {
        src = edge_ui[e];
        dst = edge_ui[E_PER_ + e] + N_USERS;
    } else {
        int e2 = e - E_PER_;
        src = N_USERS + edge_iu[e2];
        dst = edge_iu[E_PER_ + e2];
    }
}

__global__ __launch_bounds__(256) void hist_kernel(
    const int* __restrict__ edge_ui, const int* __restrict__ edge_iu,
    int* __restrict__ cnt)
{
    int e = blockIdx.x * blockDim.x + threadIdx.x;
    if (e >= E_TOT) return;
    int src, dst;
    edge_src_dst(e, edge_ui, edge_iu, src, dst);
    atomicAdd(cnt + dst, 1);
}

__global__ __launch_bounds__(256) void scan1_kernel(
    const int* __restrict__ cnt, int* __restrict__ base, int* __restrict__ bsum)
{
    __shared__ int ssum[256];
    const int t = threadIdx.x;
    const int i0 = blockIdx.x * SCAN_CHUNK + t * 4;
    int v[4];
    #pragma unroll
    for (int j = 0; j < 4; ++j) v[j] = (i0 + j < NN) ? cnt[i0 + j] : 0;
    int tsum = v[0] + v[1] + v[2] + v[3];
    ssum[t] = tsum;
    __syncthreads();
    int run = tsum;
    for (int off = 1; off < 256; off <<= 1) {
        int o = (t >= off) ? ssum[t - off] : 0;
        __syncthreads();
        run += o;
        ssum[t] = run;
        __syncthreads();
    }
    int excl = run - tsum;
    int p = excl;
    #pragma unroll
    for (int j = 0; j < 4; ++j) {
        if (i0 + j < NN) base[i0 + j] = p;
        p += v[j];
    }
    if (t == 255) bsum[blockIdx.x] = run;
}

// wave-parallel exclusive scan of SCAN_NB (<=128) block sums, 64 threads
__global__ void scan2_kernel(int* __restrict__ bsum)
{
    const int lane = threadIdx.x;   // 0..63
    int a = (lane < SCAN_NB) ? bsum[lane] : 0;
    int b = (64 + lane < SCAN_NB) ? bsum[64 + lane] : 0;
    int sa = a, sb = b;
    for (int off = 1; off < 64; off <<= 1) {
        int ta = __shfl_up(sa, off);
        int tb = __shfl_up(sb, off);
        if (lane >= off) { sa += ta; sb += tb; }
    }
    int total0 = __shfl(sa, 63);
    if (lane < SCAN_NB) bsum[lane] = sa - a;
    if (64 + lane < SCAN_NB) bsum[64 + lane] = total0 + sb - b;
}

__global__ __launch_bounds__(256) void scan3_kernel(
    int* __restrict__ base, const int* __restrict__ bsum, int* __restrict__ cursor)
{
    int i = blockIdx.x * blockDim.x + threadIdx.x;
    if (i >= NN) return;
    int b = base[i] + bsum[i >> 10];
    base[i] = b;
    cursor[i] = b;
}

__global__ __launch_bounds__(256) void fill_kernel(
    const int* __restrict__ edge_ui, const int* __restrict__ edge_iu,
    int* __restrict__ cursor, int* __restrict__ esrc)
{
    int e = blockIdx.x * blockDim.x + threadIdx.x;
    if (e >= E_TOT) return;
    int src, dst;
    edge_src_dst(e, edge_ui, edge_iu, src, dst);
    int pos = atomicAdd(cursor + dst, 1);
    esrc[pos] = src;
}

// ---------------------------------------------------------------------------
// Fused attention: wave/node, 4 edges/iter, software-pipelined gathers,
// defer-rescale (THR=8). Output written gelu'd bf16.
// ---------------------------------------------------------------------------
__global__ __launch_bounds__(256) void attn_fused(
    const unsigned short* __restrict__ q_b, const unsigned short* __restrict__ kk_b,
    const unsigned short* __restrict__ vv_b,
    const int* __restrict__ base, const int* __restrict__ cnt,
    const int* __restrict__ esrc,
    const float* __restrict__ p_ui, const float* __restrict__ p_iu,
    unsigned short* __restrict__ oa)
{
    const int wid  = (blockIdx.x * blockDim.x + threadIdx.x) >> 6;
    const int lane = threadIdx.x & 63;
    const int nw   = (gridDim.x * blockDim.x) >> 6;
    const int g    = lane >> 4;      // edge slot 0..3
    const int p    = lane & 15;      // dims 8p..8p+7
    const int h    = p >> 2;         // head
    const float rsd = 0.17677669529663687f;   // 1/sqrt(32)
    const float pu = p_ui[h], pi = p_iu[h];

    for (int n = wid; n < NN; n += nw) {
        const float pr = (n >= N_USERS) ? pu : pi;
        float qf[8];
        unpack8(*reinterpret_cast<const uint4*>(q_b + (size_t)n * 128 + p * 8), qf);
        float m = -INFINITY, l = 0.f;
        float acc[8] = {0.f, 0.f, 0.f, 0.f, 0.f, 0.f, 0.f, 0.f};
        const int s0 = base[n], c = cnt[n];

        if (c > 0) {
            bool valid = g < c;
            int src = esrc[s0 + (valid ? g : 0)];
            uint4 k4 = *reinterpret_cast<const uint4*>(kk_b + (size_t)src * 128 + p * 8);
            uint4 v4 = *reinterpret_cast<const uint4*>(vv_b + (size_t)src * 128 + p * 8);

            for (int j = 0; j < c; j += 4) {
                uint4 k4n, v4n;
                bool validn = false;
                if (j + 4 < c) {
                    int jn = j + 4 + g;
                    validn = jn < c;
                    int srcn = esrc[s0 + (validn ? jn : 0)];
                    k4n = *reinterpret_cast<const uint4*>(kk_b + (size_t)srcn * 128 + p * 8);
                    v4n = *reinterpret_cast<const uint4*>(vv_b + (size_t)srcn * 128 + p * 8);
                }

                float kf[8];
                unpack8(k4, kf);
                float s = qf[0] * kf[0];
                #pragma unroll
                for (int i = 1; i < 8; ++i) s = fmaf(qf[i], kf[i], s);
                s += __shfl_xor(s, 1);
                s += __shfl_xor(s, 2);
                float al = valid ? s * pr * rsd : -INFINITY;
                float amx = fmaxf(al, __shfl_xor(al, 16));
                amx = fmaxf(amx, __shfl_xor(amx, 32));
                if (__any(amx > m + 8.f)) {          // defer-rescale
                    float nm = fmaxf(m, amx);
                    float scale = __expf(m - nm);    // first iter: exp(-inf)=0
                    l *= scale;
                    #pragma unroll
                    for (int i = 0; i < 8; ++i) acc[i] *= scale;
                    m = nm;
                }
                float w = __expf(al - m);            // bounded by e^8; invalid -> 0
                l += w;
                float vf[8];
                unpack8(v4, vf);
                #pragma unroll
                for (int i = 0; i < 8; ++i) acc[i] = fmaf(w, vf[i], acc[i]);

                k4 = k4n; v4 = v4n; valid = validn;
            }
        }

        l += __shfl_xor(l, 16); l += __shfl_xor(l, 32);
        #pragma unroll
        for (int i = 0; i < 8; ++i) {
            acc[i] += __shfl_xor(acc[i], 16);
            acc[i] += __shfl_xor(acc[i], 32);
        }
        if (g == 0) {
            float inv = 1.0f / (l + 1e-16f);
            uint4 pk;
            unsigned o[4];
            #pragma unroll
            for (int i = 0; i < 4; ++i) {
                float lo = gelu_exact(acc[2 * i] * inv);
                float hi = gelu_exact(acc[2 * i + 1] * inv);
                o[i] = (unsigned)f2bf(lo) | ((unsigned)f2bf(hi) << 16);
            }
            pk.x = o[0]; pk.y = o[1]; pk.z = o[2]; pk.w = o[3];
            *reinterpret_cast<uint4*>(oa + (size_t)n * 128 + p * 8) = pk;
        }
    }
}

// ---------------------------------------------------------------------------
// Final GEMM, LDS-free (both sides): out = sg*(oa_gelu @ Wo + bo) + (1-sg)*x.
// oa bf16 read directly as B-fragments; Wo frag-layout; 16B f32 stores.
// ---------------------------------------------------------------------------
__global__ __launch_bounds__(256, 3) void final_mfma(
    const unsigned short* __restrict__ oa,   // [NN][128] bf16, gelu'd
    const float* __restrict__ x_u, const unsigned short* __restrict__ F_u,
    const float* __restrict__ bo_u, const float* __restrict__ skip_u,
    const float* __restrict__ x_i, const unsigned short* __restrict__ F_i,
    const float* __restrict__ bo_i, const float* __restrict__ skip_i,
    float* __restrict__ out)
{
    const int t = threadIdx.x;
    const int side = blockIdx.x >= KQV_NB;
    const int m0 = (blockIdx.x - side * KQV_NB) * 128;
    const float* x = side ? x_i : x_u;
    const unsigned short* F = side ? F_i : F_u;
    const float* bo = side ? bo_i : bo_u;
    const float* skip = side ? skip_i : skip_u;
    const int row_off = side ? N_USERS : 0;
    const int M = N_USERS;

    const int wave = t >> 6, lane = t & 63;
    const int lr = lane & 15, lg = lane >> 4;
    const int rbase = m0 + wave * 32;

    bfrag am[2][4];
    const bfrag bz = {0, 0, 0, 0, 0, 0, 0, 0};
    #pragma unroll
    for (int mt = 0; mt < 2; ++mt)
        #pragma unroll
        for (int ks = 0; ks < 4; ++ks) {
            int row = rbase + mt * 16 + lr;
            am[mt][ks] = (row < M)
                ? *reinterpret_cast<const bfrag*>(
                      oa + (size_t)(row_off + row) * 128 + ks * 32 + lg * 8)
                : bz;
        }

    f32x4 acc[2][8];
    const f32x4 zero = {0.f, 0.f, 0.f, 0.f};
    #pragma unroll
    for (int mt = 0; mt < 2; ++mt)
        #pragma unroll
        for (int nt = 0; nt < 8; ++nt) acc[mt][nt] = zero;

    bfrag bc[4], bn[4];
    #pragma unroll
    for (int ks = 0; ks < 4; ++ks)
        bc[ks] = *reinterpret_cast<const bfrag*>(
            F + ((size_t)(0 * 4 + ks) * 64 + lane) * 8);

    #pragma unroll
    for (int nt = 0; nt < 8; ++nt) {
        if (nt < 7) {
            #pragma unroll
            for (int ks = 0; ks < 4; ++ks)
                bn[ks] = *reinterpret_cast<const bfrag*>(
                    F + ((size_t)((nt + 1) * 4 + ks) * 64 + lane) * 8);
        }
        #pragma unroll
        for (int mt = 0; mt < 2; ++mt)
            #pragma unroll
            for (int ks = 0; ks < 4; ++ks)
                acc[mt][nt] = __builtin_amdgcn_mfma_f32_16x16x32_bf16(
                    bc[ks], am[mt][ks], acc[mt][nt], 0, 0, 0);
        #pragma unroll
        for (int ks = 0; ks < 4; ++ks) bc[ks] = bn[ks];
    }

    const float sg = 1.0f / (1.0f + expf(-skip[0]));
    #pragma unroll
    for (int nt = 0; nt < 8; ++nt) {
        float4 bv = *reinterpret_cast<const float4*>(bo + nt * 16 + lg * 4);
        #pragma unroll
        for (int mt = 0; mt < 2; ++mt) {
            int row = rbase + mt * 16 + lr;
            if (row < M) {
                float4 xv = *reinterpret_cast<const float4*>(
                    x + (size_t)row * 128 + nt * 16 + lg * 4);
                float4 res;
                res.x = sg * (acc[mt][nt][0] + bv.x) + (1.f - sg) * xv.x;
                res.y = sg * (acc[mt][nt][1] + bv.y) + (1.f - sg) * xv.y;
                res.z = sg * (acc[mt][nt][2] + bv.z) + (1.f - sg) * xv.z;
                res.w = sg * (acc[mt][nt][3] + bv.w) + (1.f - sg) * xv.w;
                *reinterpret_cast<float4*>(
                    out + (size_t)(row_off + row) * 128 + nt * 16 + lg * 4) = res;
            }
        }
    }
}

// ---------------------------------------------------------------------------
extern "C" void kernel_launch(void* const* d_in, const int* in_sizes, int n_in,
                              void* d_out, int out_size, void* d_ws, size_t ws_size,
                              hipStream_t stream)
{
    const float* x_user     = (const float*)d_in[0];
    const float* x_item     = (const float*)d_in[1];
    const float* W_kqv_user = (const float*)d_in[2];
    const float* b_kqv_user = (const float*)d_in[3];
    const float* W_kqv_item = (const float*)d_in[4];
    const float* b_kqv_item = (const float*)d_in[5];
    const float* Wk_rel     = (const float*)d_in[6];
    const float* Wv_rel     = (const float*)d_in[7];
    const float* W_out_user = (const float*)d_in[8];
    const float* b_out_user = (const float*)d_in[9];
    const float* W_out_item = (const float*)d_in[10];
    const float* b_out_item = (const float*)d_in[11];
    const float* skip_user  = (const float*)d_in[12];
    const float* skip_item  = (const float*)d_in[13];
    const float* p_ui       = (const float*)d_in[14];
    const float* p_iu       = (const float*)d_in[15];
    const int*   edge_ui    = (const int*)d_in[16];
    const int*   edge_iu    = (const int*)d_in[17];

    const size_t NODE_F = (size_t)NN * FDIM;     // 12.8M elems
    char* w = (char*)d_ws;
    size_t off = 0;
    auto alloc = [&](size_t bytes) {
        char* p = w + off;
        off += (bytes + 255) & ~(size_t)255;
        return p;
    };
    unsigned short* q_b   = (unsigned short*)alloc(NODE_F * 2);
    unsigned short* kk_b  = (unsigned short*)alloc(NODE_F * 2);
    unsigned short* vv_b  = (unsigned short*)alloc(NODE_F * 2);
    unsigned short* oa_b  = (unsigned short*)alloc(NODE_F * 2);
    int* esrc   = (int*)alloc((size_t)E_TOT * 4);
    int* cnt    = (int*)alloc((size_t)NN * 4);
    int* base   = (int*)alloc((size_t)NN * 4);
    int* cursor = (int*)alloc((size_t)NN * 4);
    int* bsum   = (int*)alloc((size_t)SCAN_NB * 4);
    unsigned short* F_u    = (unsigned short*)alloc(384 * 128 * 2);
    unsigned short* F_i    = (unsigned short*)alloc(384 * 128 * 2);
    float*          bias_u = (float*)alloc(384 * 4);
    float*          bias_i = (float*)alloc(384 * 4);
    unsigned short* Fo_u   = (unsigned short*)alloc(128 * 128 * 2);
    unsigned short* Fo_i   = (unsigned short*)alloc(128 * 128 * 2);

    // weight prep (fused launches, frag layout)
    prep_kqv<<<768, 128, 0, stream>>>(W_kqv_user, b_kqv_user, W_kqv_item, b_kqv_item,
                                      Wk_rel, Wv_rel, F_u, bias_u, F_i, bias_i);
    prep_wo<<<128, 256, 0, stream>>>(W_out_user, Fo_u, W_out_item, Fo_i);

    // fused KQV(+rel) GEMM, both sides, LDS-free
    kqv_mfma<<<2 * KQV_NB, 256, 0, stream>>>(x_user, F_u, bias_u,
                                             x_item, F_i, bias_i,
                                             kk_b, q_b, vv_b);

    // CSR build
    hipMemsetAsync(cnt, 0, (size_t)NN * 4, stream);
    hist_kernel<<<(E_TOT + 255) / 256, 256, 0, stream>>>(edge_ui, edge_iu, cnt);
    scan1_kernel<<<SCAN_NB, 256, 0, stream>>>(cnt, base, bsum);
    scan2_kernel<<<1, 64, 0, stream>>>(bsum);
    scan3_kernel<<<(NN + 255) / 256, 256, 0, stream>>>(base, bsum, cursor);
    fill_kernel<<<(E_TOT + 255) / 256, 256, 0, stream>>>(edge_ui, edge_iu, cursor, esrc);

    attn_fused<<<2048, 256, 0, stream>>>(q_b, kk_b, vv_b, base, cnt, esrc,
                                         p_ui, p_iu, oa_b);

    // final GEMM, both sides, LDS-free
    final_mfma<<<2 * KQV_NB, 256, 0, stream>>>(
        oa_b, x_user, Fo_u, b_out_user, skip_user,
        x_item, Fo_i, b_out_item, skip_item, (float*)d_out);
}